// Round 3
// baseline (562.618 us; speedup 1.0000x reference)
//
#include <hip/hip_runtime.h>

#define KCH 2
#define ZF 128   // Z == F == 128
#define CHUNK 256
typedef unsigned short u16;

using bf16x8_t = __attribute__((ext_vector_type(8))) short;  // MFMA A/B frag (8 bf16)
using f32x4_t  = __attribute__((ext_vector_type(4))) float;  // MFMA C/D frag

// ---------- bf16 helpers ----------
__device__ inline u16 f2bf(float f) {            // round-to-nearest-even
  unsigned u = __float_as_uint(f);
  return (u16)((u + 0x7FFF + ((u >> 16) & 1)) >> 16);
}
__device__ inline float bf2f(u16 h) { return __uint_as_float((unsigned)h << 16); }

// ---------- counting-sort utilities ----------
__global__ __launch_bounds__(256) void zero_ints(int* __restrict__ p, int n) {
  int i = blockIdx.x * 256 + threadIdx.x;
  if (i < n) p[i] = 0;
}

__global__ __launch_bounds__(256) void hist_kernel(
    const int* __restrict__ rows, int* __restrict__ cnt, int E) {
  int i = blockIdx.x * 256 + threadIdx.x;
  if (i < E) atomicAdd(&cnt[rows[i]], 1);   // 400 KB counter array: L2-resident
}

__global__ __launch_bounds__(256) void chunk_reduce(
    const int* __restrict__ cnt, int* __restrict__ chunk, int N) {
  __shared__ int s[256];
  int tid = threadIdx.x;
  int i = blockIdx.x * 256 + tid;
  s[tid] = (i < N) ? cnt[i] : 0;
  __syncthreads();
#pragma unroll
  for (int o = 128; o > 0; o >>= 1) {
    if (tid < o) s[tid] += s[tid + o];
    __syncthreads();
  }
  if (tid == 0) chunk[blockIdx.x] = s[0];
}

__global__ __launch_bounds__(512) void chunk_scan(
    int* __restrict__ chunk, int nch, int* __restrict__ row_off, int N, int E) {
  __shared__ int s[512];
  int tid = threadIdx.x;
  int v = (tid < nch) ? chunk[tid] : 0;
  s[tid] = v;
  __syncthreads();
#pragma unroll
  for (int o = 1; o < 512; o <<= 1) {
    int t = (tid >= o) ? s[tid - o] : 0;
    __syncthreads();
    s[tid] += t;
    __syncthreads();
  }
  if (tid < nch) chunk[tid] = s[tid] - v;   // exclusive
  if (tid == 0) row_off[N] = E;
}

// Exclusive scan within each 256-chunk; writes row_off AND seeds cursor.
__global__ __launch_bounds__(256) void scan_within_chunk(
    const int* __restrict__ cnt, const int* __restrict__ chunk,
    int* __restrict__ row_off, int* __restrict__ cursor, int N) {
  __shared__ int s[256];
  int tid = threadIdx.x;
  int i = blockIdx.x * 256 + tid;
  int v = (i < N) ? cnt[i] : 0;
  s[tid] = v;
  __syncthreads();
#pragma unroll
  for (int o = 1; o < 256; o <<= 1) {
    int t = (tid >= o) ? s[tid - o] : 0;
    __syncthreads();
    s[tid] += t;
    __syncthreads();
  }
  if (i < N) {
    int start = chunk[blockIdx.x] + s[tid] - v;
    row_off[i] = start;
    cursor[i] = start;
  }
}

// Scatter edges into row-sorted order as packed (col, val) int2 pairs.
__global__ __launch_bounds__(256) void bucket_kernel(
    const int* __restrict__ rows, const int* __restrict__ cols,
    const float* __restrict__ vals, int* __restrict__ cursor,
    int2* __restrict__ pairs, int E) {
  int i = blockIdx.x * 256 + threadIdx.x;
  if (i >= E) return;
  int r = rows[i];
  int p = atomicAdd(&cursor[r], 1);
  int2 pr;
  pr.x = cols[i];
  pr.y = __float_as_int(vals[i]);
  pairs[p] = pr;
}

// ---------- W -> bf16 hi/lo split, pre-arranged in MFMA A-fragment order ----------
// A-frag layout for mfma_f32_16x16x32_bf16: lane l supplies A[row=l&15][k=(l>>4)*8+j],
// j=0..7 contiguous.  A = W^T tile: A-row = f (within 16-col tile ft), A-col = k.
// Element e = ((ft*4+ks)*64 + l)*8 + j  holds W[k][f],
//   k = ks*32 + (l>>4)*8 + j,  f = ft*16 + (l&15).
// wf[0..16383] = hi, wf[16384..32767] = lo  (64 KB total).
__global__ __launch_bounds__(256) void wfrag_prep(
    const float* __restrict__ W, u16* __restrict__ wf) {
  int t = blockIdx.x * 256 + threadIdx.x;   // t = k*128 + f (coalesced read)
  if (t >= 16384) return;
  int k = t >> 7, f = t & 127;
  int ks = k >> 5, kk = k & 31;
  int lg = kk >> 3, j = kk & 7;
  int ft = f >> 4, c = f & 15;
  int l = lg * 16 + c;
  int e = ((ft * 4 + ks) * 64 + l) * 8 + j;
  float w = W[t];
  u16 hi = f2bf(w);
  u16 lo = f2bf(w - bf2f(hi));   // exact residual, then RNE
  wf[e] = hi;
  wf[16384 + e] = lo;
}

// ---------- B-fragment load+convert for one 16-node tile ----------
__device__ inline void load_bfrag(const float* __restrict__ xb,
                                  bf16x8_t* bhi, bf16x8_t* blo) {
#pragma unroll
  for (int ks = 0; ks < 4; ++ks) {
    float4 u = ((const float4*)(xb + ks * 32))[0];
    float4 v = ((const float4*)(xb + ks * 32))[1];
    float tmp[8] = {u.x, u.y, u.z, u.w, v.x, v.y, v.z, v.w};
#pragma unroll
    for (int j2 = 0; j2 < 8; ++j2) {
      u16 hi = f2bf(tmp[j2]);
      bhi[ks][j2] = (short)hi;
      blo[ks][j2] = (short)f2bf(tmp[j2] - bf2f(hi));
    }
  }
}

__device__ inline void store_tile(u16* __restrict__ dst, const f32x4_t* acc, int rg) {
#pragma unroll
  for (int ft = 0; ft < 8; ++ft) {
    ushort4 o;
    o.x = f2bf(acc[ft][0]);
    o.y = f2bf(acc[ft][1]);
    o.z = f2bf(acc[ft][2]);
    o.w = f2bf(acc[ft][3]);
    *(ushort4*)(dst + ft * 16 + rg * 4) = o;
  }
}

// ---------- support = x @ W via split-bf16 MFMA, written straight into xi ----------
// xi[node][k][f] bf16, 512 B per node (the spmm gather layout).
// Split GEMM: x_hi*W_hi + x_hi*W_lo + x_lo*W_hi  ->  fp32-accurate support;
// only quantization is the final bf16 store.
// 2 node-tiles batched per A-fragment read: 6 MFMAs per 2 ds_read_b128
// (halves LDS read traffic vs 1-tile version).
__global__ __launch_bounds__(256) void gemm_xw_bf16(
    const float* __restrict__ x, const u16* __restrict__ wf,
    u16* __restrict__ xi, int N) {
  __shared__ u16 lw[32768];   // 64 KB: [0..16383]=W_hi frags, [16384..]=W_lo frags
  int tid = threadIdx.x;
  {
    const uint4* src = (const uint4*)wf;
    uint4* dst = (uint4*)lw;
#pragma unroll
    for (int i = 0; i < 16; ++i) dst[tid + i * 256] = src[tid + i * 256];
  }
  __syncthreads();

  int l   = tid & 63;
  int col = l & 15;      // B col -> node offset within tile
  int rg  = l >> 4;      // k-group / C-row group
  int wgid = blockIdx.x * 4 + (tid >> 6);
  int nt = (KCH * N) >> 4;        // row-tiles of 16 (N%16==0 guaranteed by caller)
  int nt2 = nt >> 1;
  int nw = gridDim.x * 4;

  for (int t2 = wgid; t2 < nt2; t2 += nw) {
    int tA = t2 * 2, tB = tA + 1;
    int rowA = tA << 4, rowB = tB << 4;
    int kcA = (rowA >= N) ? 1 : 0;
    int kcB = (rowB >= N) ? 1 : 0;
    int n0A = rowA - kcA * N;
    int n0B = rowB - kcB * N;

    const float* xbA = x + (size_t)(kcA * N + n0A + col) * ZF + rg * 8;
    const float* xbB = x + (size_t)(kcB * N + n0B + col) * ZF + rg * 8;
    bf16x8_t bhiA[4], bloA[4], bhiB[4], bloB[4];
    load_bfrag(xbA, bhiA, bloA);
    load_bfrag(xbB, bhiB, bloB);

    f32x4_t accA[8], accB[8];
#pragma unroll
    for (int ft = 0; ft < 8; ++ft) { accA[ft] = {0.f,0.f,0.f,0.f}; accB[ft] = {0.f,0.f,0.f,0.f}; }

#pragma unroll
    for (int ft = 0; ft < 8; ++ft) {
#pragma unroll
      for (int ks = 0; ks < 4; ++ks) {
        int eb = ((ft * 4 + ks) * 64 + l) * 8;
        const bf16x8_t ahi = *(const bf16x8_t*)(lw + eb);
        const bf16x8_t alo = *(const bf16x8_t*)(lw + 16384 + eb);
        accA[ft] = __builtin_amdgcn_mfma_f32_16x16x32_bf16(ahi, bhiA[ks], accA[ft], 0, 0, 0);
        accA[ft] = __builtin_amdgcn_mfma_f32_16x16x32_bf16(alo, bhiA[ks], accA[ft], 0, 0, 0);
        accA[ft] = __builtin_amdgcn_mfma_f32_16x16x32_bf16(ahi, bloA[ks], accA[ft], 0, 0, 0);
        accB[ft] = __builtin_amdgcn_mfma_f32_16x16x32_bf16(ahi, bhiB[ks], accB[ft], 0, 0, 0);
        accB[ft] = __builtin_amdgcn_mfma_f32_16x16x32_bf16(alo, bhiB[ks], accB[ft], 0, 0, 0);
        accB[ft] = __builtin_amdgcn_mfma_f32_16x16x32_bf16(ahi, bloB[ks], accB[ft], 0, 0, 0);
      }
    }

    store_tile(xi + (size_t)(n0A + col) * 256 + kcA * 128, accA, rg);
    store_tile(xi + (size_t)(n0B + col) * 256 + kcB * 128, accB, rg);
  }

  // odd-tile tail (not hit for N=100k): processed by wave 0
  if ((nt & 1) && wgid == 0) {
    int t = nt - 1;
    int row0 = t << 4;
    int kc = (row0 >= N) ? 1 : 0;
    int n0 = row0 - kc * N;
    const float* xb = x + (size_t)(kc * N + n0 + col) * ZF + rg * 8;
    bf16x8_t bhi[4], blo[4];
    load_bfrag(xb, bhi, blo);
    f32x4_t acc[8];
#pragma unroll
    for (int ft = 0; ft < 8; ++ft) acc[ft] = {0.f,0.f,0.f,0.f};
#pragma unroll
    for (int ft = 0; ft < 8; ++ft) {
#pragma unroll
      for (int ks = 0; ks < 4; ++ks) {
        int eb = ((ft * 4 + ks) * 64 + l) * 8;
        const bf16x8_t ahi = *(const bf16x8_t*)(lw + eb);
        const bf16x8_t alo = *(const bf16x8_t*)(lw + 16384 + eb);
        acc[ft] = __builtin_amdgcn_mfma_f32_16x16x32_bf16(ahi, bhi[ks], acc[ft], 0, 0, 0);
        acc[ft] = __builtin_amdgcn_mfma_f32_16x16x32_bf16(alo, bhi[ks], acc[ft], 0, 0, 0);
        acc[ft] = __builtin_amdgcn_mfma_f32_16x16x32_bf16(ahi, blo[ks], acc[ft], 0, 0, 0);
      }
    }
    store_tile(xi + (size_t)(n0 + col) * 256 + kc * 128, acc, rg);
  }
}

// ---------- CSR SpMM over bf16 support: one wave per row, fused relu ----------
// 8-edge software pipeline: all 8 gathers issued before any FMA so the
// compiler can retire them with counted vmcnt (8 outstanding 512B gathers/wave).
__global__ __launch_bounds__(256) void spmm_csr_bf16(
    const u16* __restrict__ xi, const int* __restrict__ row_off,
    const int2* __restrict__ pairs, float* __restrict__ out, int N) {
  int r = blockIdx.x * 4 + (threadIdx.x >> 6);
  int lane = threadIdx.x & 63;
  if (r >= N) return;
  int beg = row_off[r];
  int end = row_off[r + 1];

  float4 acc = make_float4(0.f, 0.f, 0.f, 0.f);
  int j = beg;
  for (; j + 8 <= end; j += 8) {
    int2 p[8];
#pragma unroll
    for (int u = 0; u < 8; ++u) p[u] = pairs[j + u];
    ushort4 a[8];
#pragma unroll
    for (int u = 0; u < 8; ++u)
      a[u] = ((const ushort4*)(xi + (size_t)p[u].x * 256))[lane];
#pragma unroll
    for (int u = 0; u < 8; ++u) {
      float v = __int_as_float(p[u].y);
      acc.x = fmaf(v, bf2f(a[u].x), acc.x);
      acc.y = fmaf(v, bf2f(a[u].y), acc.y);
      acc.z = fmaf(v, bf2f(a[u].z), acc.z);
      acc.w = fmaf(v, bf2f(a[u].w), acc.w);
    }
  }
  for (; j + 4 <= end; j += 4) {
    int2 p[4];
#pragma unroll
    for (int u = 0; u < 4; ++u) p[u] = pairs[j + u];
    ushort4 a[4];
#pragma unroll
    for (int u = 0; u < 4; ++u)
      a[u] = ((const ushort4*)(xi + (size_t)p[u].x * 256))[lane];
#pragma unroll
    for (int u = 0; u < 4; ++u) {
      float v = __int_as_float(p[u].y);
      acc.x = fmaf(v, bf2f(a[u].x), acc.x);
      acc.y = fmaf(v, bf2f(a[u].y), acc.y);
      acc.z = fmaf(v, bf2f(a[u].z), acc.z);
      acc.w = fmaf(v, bf2f(a[u].w), acc.w);
    }
  }
  for (; j < end; ++j) {
    int2 p = pairs[j];
    ushort4 a = ((const ushort4*)(xi + (size_t)p.x * 256))[lane];
    float v = __int_as_float(p.y);
    acc.x = fmaf(v, bf2f(a.x), acc.x);
    acc.y = fmaf(v, bf2f(a.y), acc.y);
    acc.z = fmaf(v, bf2f(a.z), acc.z);
    acc.w = fmaf(v, bf2f(a.w), acc.w);
  }
  acc.x = fmaxf(acc.x, 0.f);
  acc.y = fmaxf(acc.y, 0.f);
  acc.z = fmaxf(acc.z, 0.f);
  acc.w = fmaxf(acc.w, 0.f);
  int k = lane >> 5;
  int g = lane & 31;
  ((float4*)(out + ((size_t)k * N + (size_t)r) * ZF))[g] = acc;
}

// ---------- mid-tier fallback: fp32 CSR SpMM (A@x, no relu; gemm pass follows) ----------
__global__ __launch_bounds__(256) void spmm_csr(
    const float* __restrict__ x, const int* __restrict__ row_off,
    const int2* __restrict__ pairs, float* __restrict__ out, int N) {
  int r = blockIdx.x * 4 + (threadIdx.x >> 6);
  int lane = threadIdx.x & 63;
  if (r >= N) return;
  int k = lane >> 5;
  int g = lane & 31;
  int beg = row_off[r];
  int end = row_off[r + 1];
  const float* xb = x + (size_t)k * N * ZF;
  float4 acc = make_float4(0.f, 0.f, 0.f, 0.f);
  for (int j = beg; j < end; ++j) {
    int2 p = pairs[j];
    float4 a = ((const float4*)(xb + (size_t)p.x * ZF))[g];
    float v = __int_as_float(p.y);
    acc.x = fmaf(v, a.x, acc.x);
    acc.y = fmaf(v, a.y, acc.y);
    acc.z = fmaf(v, a.z, acc.z);
    acc.w = fmaf(v, a.w, acc.w);
  }
  ((float4*)(out + ((size_t)k * N + (size_t)r) * ZF))[g] = acc;
}

// ---------- last-resort fallback: atomic scatter ----------
__device__ inline void atomic_add_f32(float* p, float v) {
#if defined(__HIP_DEVICE_COMPILE__) && defined(__AMDGCN__)
  unsafeAtomicAdd(p, v);
#else
  atomicAdd(p, v);
#endif
}

__global__ __launch_bounds__(256) void zero_kernel(float4* __restrict__ p, long long n4) {
  long long i = (long long)blockIdx.x * 256 + threadIdx.x;
  long long stride = (long long)gridDim.x * 256;
  for (; i < n4; i += stride) p[i] = make_float4(0.f, 0.f, 0.f, 0.f);
}

__global__ __launch_bounds__(256) void scatter_spmm_kernel(
    const float* __restrict__ x, const int* __restrict__ rows,
    const int* __restrict__ cols, const float* __restrict__ vals,
    float* __restrict__ tmp, int E, int N) {
  int t = blockIdx.x * 256 + threadIdx.x;
  int e = t >> 6;
  if (e >= E) return;
  int sub = t & 63;
  int k = sub >> 5;
  int g = sub & 31;
  int row = rows[e];
  int col = cols[e];
  float val = vals[e];
  const float4* src = (const float4*)(x + ((size_t)k * N + col) * ZF);
  float4 v = src[g];
  float* dst = tmp + ((size_t)k * N + row) * ZF + (size_t)g * 4;
  atomic_add_f32(dst + 0, val * v.x);
  atomic_add_f32(dst + 1, val * v.y);
  atomic_add_f32(dst + 2, val * v.z);
  atomic_add_f32(dst + 3, val * v.w);
}

// ---------- fallback pass 2: io[m,:] = relu(io[m,:] @ W) in place ----------
__global__ __launch_bounds__(256) void gemm_relu_inplace(
    float* __restrict__ io, const float* __restrict__ W, long long Mtotal) {
  __shared__ float Ws[64 * ZF];
  __shared__ float Xs[32 * ZF];
  int tid = threadIdx.x;
  long long row0 = (long long)blockIdx.x * 32;

  const float4* src = (const float4*)(io + row0 * ZF);
  float4* Xs4 = (float4*)Xs;
#pragma unroll
  for (int i = 0; i < 4; ++i) {
    int idx = tid + i * 256;
    long long r = row0 + (idx >> 5);
    Xs4[idx] = (r < Mtotal) ? src[idx] : make_float4(0.f, 0.f, 0.f, 0.f);
  }

  int f0 = (tid & 31) * 4;
  int rg = tid >> 5;

  float acc[4][4];
#pragma unroll
  for (int j = 0; j < 4; ++j)
#pragma unroll
    for (int i = 0; i < 4; ++i) acc[j][i] = 0.f;

  const float4* W4 = (const float4*)W;
  float4* Ws4 = (float4*)Ws;

  for (int zh = 0; zh < 2; ++zh) {
    __syncthreads();
#pragma unroll
    for (int i = 0; i < 8; ++i) {
      int idx = tid + i * 256;
      Ws4[idx] = W4[(size_t)zh * 2048 + idx];
    }
    __syncthreads();

#pragma unroll 4
    for (int z = 0; z < 64; ++z) {
      float4 wv = *(const float4*)(Ws + z * ZF + f0);
#pragma unroll
      for (int j = 0; j < 4; ++j) {
        float xv = Xs[(rg + 8 * j) * ZF + (zh * 64 + z)];
        acc[j][0] = fmaf(xv, wv.x, acc[j][0]);
        acc[j][1] = fmaf(xv, wv.y, acc[j][1]);
        acc[j][2] = fmaf(xv, wv.z, acc[j][2]);
        acc[j][3] = fmaf(xv, wv.w, acc[j][3]);
      }
    }
  }

#pragma unroll
  for (int j = 0; j < 4; ++j) {
    long long r = row0 + rg + 8 * j;
    if (r < Mtotal) {
      float4 o;
      o.x = fmaxf(acc[j][0], 0.f);
      o.y = fmaxf(acc[j][1], 0.f);
      o.z = fmaxf(acc[j][2], 0.f);
      o.w = fmaxf(acc[j][3], 0.f);
      *(float4*)(io + r * ZF + f0) = o;
    }
  }
}

extern "C" void kernel_launch(void* const* d_in, const int* in_sizes, int n_in,
                              void* d_out, int out_size, void* d_ws, size_t ws_size,
                              hipStream_t stream) {
  const float* x    = (const float*)d_in[0];   // [K, N, Z]
  const int*   rows = (const int*)d_in[1];     // [E]
  const int*   cols = (const int*)d_in[2];     // [E]
  const float* vals = (const float*)d_in[3];   // [E]
  const float* W    = (const float*)d_in[4];   // [Z, F]

  int E = in_sizes[1];
  int N = in_sizes[0] / (KCH * ZF);
  float* out = (float*)d_out;

  int nch = (N + CHUNK - 1) / CHUNK;           // 391 for N=100k (must be <= 512)

  size_t off = 0;
  auto carve = [&](size_t bytes) {
    size_t p = off;
    off += (bytes + 15) & ~(size_t)15;
    return (char*)d_ws + p;
  };
  int*  row_off = (int*)carve((size_t)(N + 1) * 4);
  int*  cursor  = (int*)carve((size_t)N * 4);
  int*  chunk   = (int*)carve((size_t)nch * 4);
  int2* pairs   = (int2*)carve((size_t)E * 8);
  size_t off_csr = off;
  u16*  wf      = (u16*)carve(65536);                      // W hi/lo frags (64 KB)
  u16*  xi      = (u16*)carve((size_t)N * KCH * ZF * 2);   // 51.2 MB support (bf16)

  bool csr_ok  = (off_csr <= ws_size) && (nch <= 512);
  bool bf16_ok = (off <= ws_size) && (nch <= 512) && ((N & 15) == 0);

  if (csr_ok) {
    int nb_N = (N + 255) / 256;
    int nb_E = (E + 255) / 256;

    zero_ints<<<nb_N, 256, 0, stream>>>(cursor, N);
    hist_kernel<<<nb_E, 256, 0, stream>>>(rows, cursor, E);
    chunk_reduce<<<nch, 256, 0, stream>>>(cursor, chunk, N);
    chunk_scan<<<1, 512, 0, stream>>>(chunk, nch, row_off, N, E);
    scan_within_chunk<<<nch, 256, 0, stream>>>(cursor, chunk, row_off, cursor, N);
    bucket_kernel<<<nb_E, 256, 0, stream>>>(rows, cols, vals, cursor, pairs, E);

    int sblocks = (N + 3) / 4;
    if (bf16_ok) {
      wfrag_prep<<<64, 256, 0, stream>>>(W, wf);
      gemm_xw_bf16<<<512, 256, 0, stream>>>(x, wf, xi, N);
      spmm_csr_bf16<<<sblocks, 256, 0, stream>>>(xi, row_off, pairs, out, N);
    } else {
      spmm_csr<<<sblocks, 256, 0, stream>>>(x, row_off, pairs, out, N);
      long long Mtotal = (long long)KCH * N;
      int mblocks = (int)((Mtotal + 31) / 32);
      gemm_relu_inplace<<<mblocks, 256, 0, stream>>>(out, W, Mtotal);
    }
  } else {
    long long n4 = (long long)out_size / 4;
    int zblocks = (int)((n4 + 255) / 256);
    zero_kernel<<<zblocks, 256, 0, stream>>>((float4*)out, n4);
    long long total_threads = (long long)E * 64;
    int sblocks = (int)((total_threads + 255) / 256);
    scatter_spmm_kernel<<<sblocks, 256, 0, stream>>>(x, rows, cols, vals, out, E, N);
    long long Mtotal = (long long)KCH * N;
    int mblocks = (int)((Mtotal + 31) / 32);
    gemm_relu_inplace<<<mblocks, 256, 0, stream>>>(out, W, Mtotal);
  }
}

// Round 4
// 556.203 us; speedup vs baseline: 1.0115x; 1.0115x over previous
//
#include <hip/hip_runtime.h>

#define KCH 2
#define ZF 128   // Z == F == 128
#define CHUNK 256
typedef unsigned short u16;

using bf16x8_t = __attribute__((ext_vector_type(8))) short;  // MFMA A/B frag (8 bf16)
using f32x4_t  = __attribute__((ext_vector_type(4))) float;  // MFMA C/D frag

// ---------- bf16 helpers ----------
__device__ inline u16 f2bf(float f) {            // round-to-nearest-even
  unsigned u = __float_as_uint(f);
  return (u16)((u + 0x7FFF + ((u >> 16) & 1)) >> 16);
}
__device__ inline float bf2f(u16 h) { return __uint_as_float((unsigned)h << 16); }
__device__ inline float bflo(unsigned w) { return __uint_as_float(w << 16); }
__device__ inline float bfhi(unsigned w) { return __uint_as_float(w & 0xFFFF0000u); }

// ---------- counting-sort utilities ----------
__global__ __launch_bounds__(256) void zero_ints(int* __restrict__ p, int n) {
  int i = blockIdx.x * 256 + threadIdx.x;
  if (i < n) p[i] = 0;
}

__global__ __launch_bounds__(256) void hist_kernel(
    const int* __restrict__ rows, int* __restrict__ cnt, int E) {
  int i = blockIdx.x * 256 + threadIdx.x;
  if (i < E) atomicAdd(&cnt[rows[i]], 1);   // 400 KB counter array: L2-resident
}

__global__ __launch_bounds__(256) void chunk_reduce(
    const int* __restrict__ cnt, int* __restrict__ chunk, int N) {
  __shared__ int s[256];
  int tid = threadIdx.x;
  int i = blockIdx.x * 256 + tid;
  s[tid] = (i < N) ? cnt[i] : 0;
  __syncthreads();
#pragma unroll
  for (int o = 128; o > 0; o >>= 1) {
    if (tid < o) s[tid] += s[tid + o];
    __syncthreads();
  }
  if (tid == 0) chunk[blockIdx.x] = s[0];
}

__global__ __launch_bounds__(512) void chunk_scan(
    int* __restrict__ chunk, int nch, int* __restrict__ row_off, int N, int E) {
  __shared__ int s[512];
  int tid = threadIdx.x;
  int v = (tid < nch) ? chunk[tid] : 0;
  s[tid] = v;
  __syncthreads();
#pragma unroll
  for (int o = 1; o < 512; o <<= 1) {
    int t = (tid >= o) ? s[tid - o] : 0;
    __syncthreads();
    s[tid] += t;
    __syncthreads();
  }
  if (tid < nch) chunk[tid] = s[tid] - v;   // exclusive
  if (tid == 0) row_off[N] = E;
}

// Exclusive scan within each 256-chunk; writes row_off AND seeds cursor.
__global__ __launch_bounds__(256) void scan_within_chunk(
    const int* __restrict__ cnt, const int* __restrict__ chunk,
    int* __restrict__ row_off, int* __restrict__ cursor, int N) {
  __shared__ int s[256];
  int tid = threadIdx.x;
  int i = blockIdx.x * 256 + tid;
  int v = (i < N) ? cnt[i] : 0;
  s[tid] = v;
  __syncthreads();
#pragma unroll
  for (int o = 1; o < 256; o <<= 1) {
    int t = (tid >= o) ? s[tid - o] : 0;
    __syncthreads();
    s[tid] += t;
    __syncthreads();
  }
  if (i < N) {
    int start = chunk[blockIdx.x] + s[tid] - v;
    row_off[i] = start;
    cursor[i] = start;
  }
}

// Scatter edges into row-sorted order as packed (col, val) int2 pairs.
__global__ __launch_bounds__(256) void bucket_kernel(
    const int* __restrict__ rows, const int* __restrict__ cols,
    const float* __restrict__ vals, int* __restrict__ cursor,
    int2* __restrict__ pairs, int E) {
  int i = blockIdx.x * 256 + threadIdx.x;
  if (i >= E) return;
  int r = rows[i];
  int p = atomicAdd(&cursor[r], 1);
  int2 pr;
  pr.x = cols[i];
  pr.y = __float_as_int(vals[i]);
  pairs[p] = pr;
}

// ---------- W -> bf16 hi/lo split, pre-arranged in MFMA A-fragment order ----------
// A-frag layout for mfma_f32_16x16x32_bf16: lane l supplies A[row=l&15][k=(l>>4)*8+j],
// j=0..7 contiguous.  A = W^T tile: A-row = f (within 16-col tile ft), A-col = k.
// Element e = ((ft*4+ks)*64 + l)*8 + j  holds W[k][f],
//   k = ks*32 + (l>>4)*8 + j,  f = ft*16 + (l&15).
// wf[0..16383] = hi, wf[16384..32767] = lo  (64 KB total).
__global__ __launch_bounds__(256) void wfrag_prep(
    const float* __restrict__ W, u16* __restrict__ wf) {
  int t = blockIdx.x * 256 + threadIdx.x;   // t = k*128 + f (coalesced read)
  if (t >= 16384) return;
  int k = t >> 7, f = t & 127;
  int ks = k >> 5, kk = k & 31;
  int lg = kk >> 3, j = kk & 7;
  int ft = f >> 4, c = f & 15;
  int l = lg * 16 + c;
  int e = ((ft * 4 + ks) * 64 + l) * 8 + j;
  float w = W[t];
  u16 hi = f2bf(w);
  u16 lo = f2bf(w - bf2f(hi));   // exact residual, then RNE
  wf[e] = hi;
  wf[16384 + e] = lo;
}

// ---------- support = x @ W via split-bf16 MFMA, written straight into xi ----------
// xi[node][k][f] bf16, 512 B per node (the spmm gather layout).
// Split GEMM: x_hi*W_hi + x_hi*W_lo + x_lo*W_hi  ->  fp32-accurate support;
// only quantization is the final bf16 store.  (Round-2 single-tile version:
// the 2-tile batched variant regressed ~18us -- register pressure.)
__global__ __launch_bounds__(256) void gemm_xw_bf16(
    const float* __restrict__ x, const u16* __restrict__ wf,
    u16* __restrict__ xi, int N) {
  __shared__ u16 lw[32768];   // 64 KB: [0..16383]=W_hi frags, [16384..]=W_lo frags
  int tid = threadIdx.x;
  {
    const uint4* src = (const uint4*)wf;
    uint4* dst = (uint4*)lw;
#pragma unroll
    for (int i = 0; i < 16; ++i) dst[tid + i * 256] = src[tid + i * 256];
  }
  __syncthreads();

  int l   = tid & 63;
  int col = l & 15;      // B col -> node offset within tile
  int rg  = l >> 4;      // k-group / C-row group
  int wgid = blockIdx.x * 4 + (tid >> 6);
  int nt = (KCH * N) >> 4;        // row-tiles of 16 (N%16==0 guaranteed by caller)
  int nw = gridDim.x * 4;

  for (int t = wgid; t < nt; t += nw) {
    int row0 = t << 4;                       // row in M = K*N
    int kc = (row0 >= N) ? 1 : 0;            // tiles never straddle kc (N%16==0)
    int n0 = row0 - kc * N;

    // B frags: B[k][col] = x[kc][n0+col][k]; lane reads 32 B contiguous per kstep.
    const float* xb = x + (size_t)(kc * N + n0 + col) * ZF + rg * 8;
    bf16x8_t bhi[4], blo[4];
#pragma unroll
    for (int ks = 0; ks < 4; ++ks) {
      float4 u = ((const float4*)(xb + ks * 32))[0];
      float4 v = ((const float4*)(xb + ks * 32))[1];
      float tmp[8] = {u.x, u.y, u.z, u.w, v.x, v.y, v.z, v.w};
#pragma unroll
      for (int j = 0; j < 8; ++j) {
        u16 hi = f2bf(tmp[j]);
        bhi[ks][j] = (short)hi;
        blo[ks][j] = (short)f2bf(tmp[j] - bf2f(hi));
      }
    }

    f32x4_t acc[8];
#pragma unroll
    for (int ft = 0; ft < 8; ++ft) acc[ft] = {0.f, 0.f, 0.f, 0.f};

#pragma unroll
    for (int ft = 0; ft < 8; ++ft) {
#pragma unroll
      for (int ks = 0; ks < 4; ++ks) {
        int eb = ((ft * 4 + ks) * 64 + l) * 8;
        const bf16x8_t ahi = *(const bf16x8_t*)(lw + eb);           // lane-contiguous,
        const bf16x8_t alo = *(const bf16x8_t*)(lw + 16384 + eb);   // conflict-free b128
        acc[ft] = __builtin_amdgcn_mfma_f32_16x16x32_bf16(ahi, bhi[ks], acc[ft], 0, 0, 0);
        acc[ft] = __builtin_amdgcn_mfma_f32_16x16x32_bf16(alo, bhi[ks], acc[ft], 0, 0, 0);
        acc[ft] = __builtin_amdgcn_mfma_f32_16x16x32_bf16(ahi, blo[ks], acc[ft], 0, 0, 0);
      }
    }

    // C layout: D[row=(l>>4)*4+r][col=l&15]; f = ft*16 + rg*4 + r  -> contiguous ushort4.
    u16* dst = xi + (size_t)(n0 + col) * 256 + kc * 128;
#pragma unroll
    for (int ft = 0; ft < 8; ++ft) {
      ushort4 o;
      o.x = f2bf(acc[ft][0]);
      o.y = f2bf(acc[ft][1]);
      o.z = f2bf(acc[ft][2]);
      o.w = f2bf(acc[ft][3]);
      *(ushort4*)(dst + ft * 16 + rg * 4) = o;
    }
  }
}

// ---------- CSR SpMM over bf16 support: one wave per row, fused relu ----------
// 2 edges per gather instruction: lane loads 16B (dwordx4); lanes 0-31 cover
// edge j's full 512B node block, lanes 32-63 cover edge j+1's.  Halves the
// vmem instruction count vs the 8B/lane version (tests the issue-rate-bound
// hypothesis; byte traffic is already near the 8-XCD replication floor).
// Even/odd partial sums are merged once per row via shfl_down(32).
__global__ __launch_bounds__(256) void spmm_csr_bf16(
    const u16* __restrict__ xi, const int* __restrict__ row_off,
    const int2* __restrict__ pairs, float* __restrict__ out, int N) {
  int r = blockIdx.x * 4 + (threadIdx.x >> 6);
  int lane = threadIdx.x & 63;
  if (r >= N) return;
  int half = lane >> 5;    // 0: even-index edges, 1: odd-index edges
  int l16  = lane & 31;    // which 16B slot of the 512B node block
  int beg = row_off[r];
  int end = row_off[r + 1];

  float acc[8] = {0.f, 0.f, 0.f, 0.f, 0.f, 0.f, 0.f, 0.f};

  int j = beg;
  for (; j + 8 <= end; j += 8) {        // 8 edges = 4 gather instructions in flight
    int2 p[4];
#pragma unroll
    for (int u = 0; u < 4; ++u) p[u] = pairs[j + 2 * u + half];
    uint4 a[4];
#pragma unroll
    for (int u = 0; u < 4; ++u)
      a[u] = ((const uint4*)(xi + (size_t)p[u].x * 256))[l16];
#pragma unroll
    for (int u = 0; u < 4; ++u) {
      float v = __int_as_float(p[u].y);
      unsigned w;
      w = a[u].x; acc[0] = fmaf(v, bflo(w), acc[0]); acc[1] = fmaf(v, bfhi(w), acc[1]);
      w = a[u].y; acc[2] = fmaf(v, bflo(w), acc[2]); acc[3] = fmaf(v, bfhi(w), acc[3]);
      w = a[u].z; acc[4] = fmaf(v, bflo(w), acc[4]); acc[5] = fmaf(v, bfhi(w), acc[5]);
      w = a[u].w; acc[6] = fmaf(v, bflo(w), acc[6]); acc[7] = fmaf(v, bfhi(w), acc[7]);
    }
  }
  for (; j + 2 <= end; j += 2) {        // 2-edge steps
    int2 p = pairs[j + half];
    uint4 a = ((const uint4*)(xi + (size_t)p.x * 256))[l16];
    float v = __int_as_float(p.y);
    unsigned w;
    w = a.x; acc[0] = fmaf(v, bflo(w), acc[0]); acc[1] = fmaf(v, bfhi(w), acc[1]);
    w = a.y; acc[2] = fmaf(v, bflo(w), acc[2]); acc[3] = fmaf(v, bfhi(w), acc[3]);
    w = a.z; acc[4] = fmaf(v, bflo(w), acc[4]); acc[5] = fmaf(v, bfhi(w), acc[5]);
    w = a.w; acc[6] = fmaf(v, bflo(w), acc[6]); acc[7] = fmaf(v, bfhi(w), acc[7]);
  }
  if (j < end) {                        // single trailing edge: upper half contributes 0
    int2 p = pairs[j];
    uint4 a = ((const uint4*)(xi + (size_t)p.x * 256))[l16];
    float v = half ? 0.f : __int_as_float(p.y);
    unsigned w;
    w = a.x; acc[0] = fmaf(v, bflo(w), acc[0]); acc[1] = fmaf(v, bfhi(w), acc[1]);
    w = a.y; acc[2] = fmaf(v, bflo(w), acc[2]); acc[3] = fmaf(v, bfhi(w), acc[3]);
    w = a.z; acc[4] = fmaf(v, bflo(w), acc[4]); acc[5] = fmaf(v, bfhi(w), acc[5]);
    w = a.w; acc[6] = fmaf(v, bflo(w), acc[6]); acc[7] = fmaf(v, bfhi(w), acc[7]);
  }

  // merge even/odd halves: lane l (<32) += lane l+32
#pragma unroll
  for (int i = 0; i < 8; ++i) {
    float o = __shfl_down(acc[i], 32, 64);
    acc[i] += o;
  }

  if (lane < 32) {
    int k  = l16 >> 4;                  // 16B slot -> (k, f0)
    int f0 = (l16 & 15) * 8;
    float4 o0, o1;
    o0.x = fmaxf(acc[0], 0.f);
    o0.y = fmaxf(acc[1], 0.f);
    o0.z = fmaxf(acc[2], 0.f);
    o0.w = fmaxf(acc[3], 0.f);
    o1.x = fmaxf(acc[4], 0.f);
    o1.y = fmaxf(acc[5], 0.f);
    o1.z = fmaxf(acc[6], 0.f);
    o1.w = fmaxf(acc[7], 0.f);
    float* dst = out + ((size_t)k * N + (size_t)r) * ZF + f0;
    *(float4*)(dst + 0) = o0;
    *(float4*)(dst + 4) = o1;
  }
}

// ---------- mid-tier fallback: fp32 CSR SpMM (A@x, no relu; gemm pass follows) ----------
__global__ __launch_bounds__(256) void spmm_csr(
    const float* __restrict__ x, const int* __restrict__ row_off,
    const int2* __restrict__ pairs, float* __restrict__ out, int N) {
  int r = blockIdx.x * 4 + (threadIdx.x >> 6);
  int lane = threadIdx.x & 63;
  if (r >= N) return;
  int k = lane >> 5;
  int g = lane & 31;
  int beg = row_off[r];
  int end = row_off[r + 1];
  const float* xb = x + (size_t)k * N * ZF;
  float4 acc = make_float4(0.f, 0.f, 0.f, 0.f);
  for (int j = beg; j < end; ++j) {
    int2 p = pairs[j];
    float4 a = ((const float4*)(xb + (size_t)p.x * ZF))[g];
    float v = __int_as_float(p.y);
    acc.x = fmaf(v, a.x, acc.x);
    acc.y = fmaf(v, a.y, acc.y);
    acc.z = fmaf(v, a.z, acc.z);
    acc.w = fmaf(v, a.w, acc.w);
  }
  ((float4*)(out + ((size_t)k * N + (size_t)r) * ZF))[g] = acc;
}

// ---------- last-resort fallback: atomic scatter ----------
__device__ inline void atomic_add_f32(float* p, float v) {
#if defined(__HIP_DEVICE_COMPILE__) && defined(__AMDGCN__)
  unsafeAtomicAdd(p, v);
#else
  atomicAdd(p, v);
#endif
}

__global__ __launch_bounds__(256) void zero_kernel(float4* __restrict__ p, long long n4) {
  long long i = (long long)blockIdx.x * 256 + threadIdx.x;
  long long stride = (long long)gridDim.x * 256;
  for (; i < n4; i += stride) p[i] = make_float4(0.f, 0.f, 0.f, 0.f);
}

__global__ __launch_bounds__(256) void scatter_spmm_kernel(
    const float* __restrict__ x, const int* __restrict__ rows,
    const int* __restrict__ cols, const float* __restrict__ vals,
    float* __restrict__ tmp, int E, int N) {
  int t = blockIdx.x * 256 + threadIdx.x;
  int e = t >> 6;
  if (e >= E) return;
  int sub = t & 63;
  int k = sub >> 5;
  int g = sub & 31;
  int row = rows[e];
  int col = cols[e];
  float val = vals[e];
  const float4* src = (const float4*)(x + ((size_t)k * N + col) * ZF);
  float4 v = src[g];
  float* dst = tmp + ((size_t)k * N + row) * ZF + (size_t)g * 4;
  atomic_add_f32(dst + 0, val * v.x);
  atomic_add_f32(dst + 1, val * v.y);
  atomic_add_f32(dst + 2, val * v.z);
  atomic_add_f32(dst + 3, val * v.w);
}

// ---------- fallback pass 2: io[m,:] = relu(io[m,:] @ W) in place ----------
__global__ __launch_bounds__(256) void gemm_relu_inplace(
    float* __restrict__ io, const float* __restrict__ W, long long Mtotal) {
  __shared__ float Ws[64 * ZF];
  __shared__ float Xs[32 * ZF];
  int tid = threadIdx.x;
  long long row0 = (long long)blockIdx.x * 32;

  const float4* src = (const float4*)(io + row0 * ZF);
  float4* Xs4 = (float4*)Xs;
#pragma unroll
  for (int i = 0; i < 4; ++i) {
    int idx = tid + i * 256;
    long long r = row0 + (idx >> 5);
    Xs4[idx] = (r < Mtotal) ? src[idx] : make_float4(0.f, 0.f, 0.f, 0.f);
  }

  int f0 = (tid & 31) * 4;
  int rg = tid >> 5;

  float acc[4][4];
#pragma unroll
  for (int j = 0; j < 4; ++j)
#pragma unroll
    for (int i = 0; i < 4; ++i) acc[j][i] = 0.f;

  const float4* W4 = (const float4*)W;
  float4* Ws4 = (float4*)Ws;

  for (int zh = 0; zh < 2; ++zh) {
    __syncthreads();
#pragma unroll
    for (int i = 0; i < 8; ++i) {
      int idx = tid + i * 256;
      Ws4[idx] = W4[(size_t)zh * 2048 + idx];
    }
    __syncthreads();

#pragma unroll 4
    for (int z = 0; z < 64; ++z) {
      float4 wv = *(const float4*)(Ws + z * ZF + f0);
#pragma unroll
      for (int j = 0; j < 4; ++j) {
        float xv = Xs[(rg + 8 * j) * ZF + (zh * 64 + z)];
        acc[j][0] = fmaf(xv, wv.x, acc[j][0]);
        acc[j][1] = fmaf(xv, wv.y, acc[j][1]);
        acc[j][2] = fmaf(xv, wv.z, acc[j][2]);
        acc[j][3] = fmaf(xv, wv.w, acc[j][3]);
      }
    }
  }

#pragma unroll
  for (int j = 0; j < 4; ++j) {
    long long r = row0 + rg + 8 * j;
    if (r < Mtotal) {
      float4 o;
      o.x = fmaxf(acc[j][0], 0.f);
      o.y = fmaxf(acc[j][1], 0.f);
      o.z = fmaxf(acc[j][2], 0.f);
      o.w = fmaxf(acc[j][3], 0.f);
      *(float4*)(io + r * ZF + f0) = o;
    }
  }
}

extern "C" void kernel_launch(void* const* d_in, const int* in_sizes, int n_in,
                              void* d_out, int out_size, void* d_ws, size_t ws_size,
                              hipStream_t stream) {
  const float* x    = (const float*)d_in[0];   // [K, N, Z]
  const int*   rows = (const int*)d_in[1];     // [E]
  const int*   cols = (const int*)d_in[2];     // [E]
  const float* vals = (const float*)d_in[3];   // [E]
  const float* W    = (const float*)d_in[4];   // [Z, F]

  int E = in_sizes[1];
  int N = in_sizes[0] / (KCH * ZF);
  float* out = (float*)d_out;

  int nch = (N + CHUNK - 1) / CHUNK;           // 391 for N=100k (must be <= 512)

  size_t off = 0;
  auto carve = [&](size_t bytes) {
    size_t p = off;
    off += (bytes + 15) & ~(size_t)15;
    return (char*)d_ws + p;
  };
  int*  row_off = (int*)carve((size_t)(N + 1) * 4);
  int*  cursor  = (int*)carve((size_t)N * 4);
  int*  chunk   = (int*)carve((size_t)nch * 4);
  int2* pairs   = (int2*)carve((size_t)E * 8);
  size_t off_csr = off;
  u16*  wf      = (u16*)carve(65536);                      // W hi/lo frags (64 KB)
  u16*  xi      = (u16*)carve((size_t)N * KCH * ZF * 2);   // 51.2 MB support (bf16)

  bool csr_ok  = (off_csr <= ws_size) && (nch <= 512);
  bool bf16_ok = (off <= ws_size) && (nch <= 512) && ((N & 15) == 0);

  if (csr_ok) {
    int nb_N = (N + 255) / 256;
    int nb_E = (E + 255) / 256;

    zero_ints<<<nb_N, 256, 0, stream>>>(cursor, N);
    hist_kernel<<<nb_E, 256, 0, stream>>>(rows, cursor, E);
    chunk_reduce<<<nch, 256, 0, stream>>>(cursor, chunk, N);
    chunk_scan<<<1, 512, 0, stream>>>(chunk, nch, row_off, N, E);
    scan_within_chunk<<<nch, 256, 0, stream>>>(cursor, chunk, row_off, cursor, N);
    bucket_kernel<<<nb_E, 256, 0, stream>>>(rows, cols, vals, cursor, pairs, E);

    int sblocks = (N + 3) / 4;
    if (bf16_ok) {
      wfrag_prep<<<64, 256, 0, stream>>>(W, wf);
      gemm_xw_bf16<<<512, 256, 0, stream>>>(x, wf, xi, N);
      spmm_csr_bf16<<<sblocks, 256, 0, stream>>>(xi, row_off, pairs, out, N);
    } else {
      spmm_csr<<<sblocks, 256, 0, stream>>>(x, row_off, pairs, out, N);
      long long Mtotal = (long long)KCH * N;
      int mblocks = (int)((Mtotal + 31) / 32);
      gemm_relu_inplace<<<mblocks, 256, 0, stream>>>(out, W, Mtotal);
    }
  } else {
    long long n4 = (long long)out_size / 4;
    int zblocks = (int)((n4 + 255) / 256);
    zero_kernel<<<zblocks, 256, 0, stream>>>((float4*)out, n4);
    long long total_threads = (long long)E * 64;
    int sblocks = (int)((total_threads + 255) / 256);
    scatter_spmm_kernel<<<sblocks, 256, 0, stream>>>(x, rows, cols, vals, out, E, N);
    long long Mtotal = (long long)KCH * N;
    int mblocks = (int)((Mtotal + 31) / 32);
    gemm_relu_inplace<<<mblocks, 256, 0, stream>>>(out, W, Mtotal);
  }
}

// Round 6
// 552.670 us; speedup vs baseline: 1.0180x; 1.0064x over previous
//
#include <hip/hip_runtime.h>

#define KCH 2
#define ZF 128   // Z == F == 128
#define CHUNK 256
typedef unsigned short u16;

using bf16x8_t = __attribute__((ext_vector_type(8))) short;  // MFMA A/B frag (8 bf16)
using f32x4_t  = __attribute__((ext_vector_type(4))) float;  // MFMA C/D frag
using f32x4n   = __attribute__((ext_vector_type(4))) float;  // native vec for nontemporal builtins

// ---------- bf16 helpers ----------
__device__ inline u16 f2bf(float f) {            // round-to-nearest-even
  unsigned u = __float_as_uint(f);
  return (u16)((u + 0x7FFF + ((u >> 16) & 1)) >> 16);
}
__device__ inline float bf2f(u16 h) { return __uint_as_float((unsigned)h << 16); }

// ---------- counting-sort utilities ----------
// zero cursor AND build W fragments in one dispatch (independent work;
// saves a launch gap).  Blocks [0,nbN): zero. Blocks [nbN, nbN+64): wfrag.
__global__ __launch_bounds__(256) void zero_and_wfrag(
    int* __restrict__ p, int n, int nbN,
    const float* __restrict__ W, u16* __restrict__ wf) {
  if ((int)blockIdx.x < nbN) {
    int i = blockIdx.x * 256 + threadIdx.x;
    if (i < n) p[i] = 0;
    return;
  }
  // W -> bf16 hi/lo split, pre-arranged in MFMA A-fragment order.
  // A-frag layout for mfma_f32_16x16x32_bf16: lane l supplies
  // A[row=l&15][k=(l>>4)*8+j], j=0..7 contiguous.  A = W^T tile.
  // Element e = ((ft*4+ks)*64 + l)*8 + j holds W[k][f],
  //   k = ks*32 + (l>>4)*8 + j,  f = ft*16 + (l&15).
  int t = (blockIdx.x - nbN) * 256 + threadIdx.x;   // t = k*128 + f
  if (t >= 16384) return;
  int k = t >> 7, f = t & 127;
  int ks = k >> 5, kk = k & 31;
  int lg = kk >> 3, j = kk & 7;
  int ft = f >> 4, c = f & 15;
  int l = lg * 16 + c;
  int e = ((ft * 4 + ks) * 64 + l) * 8 + j;
  float w = W[t];
  u16 hi = f2bf(w);
  u16 lo = f2bf(w - bf2f(hi));   // exact residual, then RNE
  wf[e] = hi;
  wf[16384 + e] = lo;
}

__global__ __launch_bounds__(256) void hist_kernel(
    const int* __restrict__ rows, int* __restrict__ cnt, int E) {
  int i = blockIdx.x * 256 + threadIdx.x;
  if (i < E) atomicAdd(&cnt[rows[i]], 1);   // 400 KB counter array: L2-resident
}

__global__ __launch_bounds__(256) void chunk_reduce(
    const int* __restrict__ cnt, int* __restrict__ chunk, int N) {
  __shared__ int s[256];
  int tid = threadIdx.x;
  int i = blockIdx.x * 256 + tid;
  s[tid] = (i < N) ? cnt[i] : 0;
  __syncthreads();
#pragma unroll
  for (int o = 128; o > 0; o >>= 1) {
    if (tid < o) s[tid] += s[tid + o];
    __syncthreads();
  }
  if (tid == 0) chunk[blockIdx.x] = s[0];
}

__global__ __launch_bounds__(512) void chunk_scan(
    int* __restrict__ chunk, int nch, int* __restrict__ row_off, int N, int E) {
  __shared__ int s[512];
  int tid = threadIdx.x;
  int v = (tid < nch) ? chunk[tid] : 0;
  s[tid] = v;
  __syncthreads();
#pragma unroll
  for (int o = 1; o < 512; o <<= 1) {
    int t = (tid >= o) ? s[tid - o] : 0;
    __syncthreads();
    s[tid] += t;
    __syncthreads();
  }
  if (tid < nch) chunk[tid] = s[tid] - v;   // exclusive
  if (tid == 0) row_off[N] = E;
}

// Exclusive scan within each 256-chunk; writes row_off AND seeds cursor.
__global__ __launch_bounds__(256) void scan_within_chunk(
    const int* __restrict__ cnt, const int* __restrict__ chunk,
    int* __restrict__ row_off, int* __restrict__ cursor, int N) {
  __shared__ int s[256];
  int tid = threadIdx.x;
  int i = blockIdx.x * 256 + tid;
  int v = (i < N) ? cnt[i] : 0;
  s[tid] = v;
  __syncthreads();
#pragma unroll
  for (int o = 1; o < 256; o <<= 1) {
    int t = (tid >= o) ? s[tid - o] : 0;
    __syncthreads();
    s[tid] += t;
    __syncthreads();
  }
  if (i < N) {
    int start = chunk[blockIdx.x] + s[tid] - v;
    row_off[i] = start;
    cursor[i] = start;
  }
}

// Scatter edges into row-sorted order as packed (col, val) int2 pairs.
__global__ __launch_bounds__(256) void bucket_kernel(
    const int* __restrict__ rows, const int* __restrict__ cols,
    const float* __restrict__ vals, int* __restrict__ cursor,
    int2* __restrict__ pairs, int E) {
  int i = blockIdx.x * 256 + threadIdx.x;
  if (i >= E) return;
  int r = rows[i];
  int p = atomicAdd(&cursor[r], 1);
  int2 pr;
  pr.x = cols[i];
  pr.y = __float_as_int(vals[i]);
  pairs[p] = pr;
}

// ---------- support = x @ W via split-bf16 MFMA, written straight into xi ----------
// xi[node][k][f] bf16, 512 B per node (the spmm gather layout).
// Split GEMM: x_hi*W_hi + x_hi*W_lo + x_lo*W_hi  ->  fp32-accurate support;
// only quantization is the final bf16 store.
// x loads are NON-TEMPORAL (read-once) so x doesn't evict xi from L3.
__global__ __launch_bounds__(256) void gemm_xw_bf16(
    const float* __restrict__ x, const u16* __restrict__ wf,
    u16* __restrict__ xi, int N) {
  __shared__ u16 lw[32768];   // 64 KB: [0..16383]=W_hi frags, [16384..]=W_lo frags
  int tid = threadIdx.x;
  {
    const uint4* src = (const uint4*)wf;
    uint4* dst = (uint4*)lw;
#pragma unroll
    for (int i = 0; i < 16; ++i) dst[tid + i * 256] = src[tid + i * 256];
  }
  __syncthreads();

  int l   = tid & 63;
  int col = l & 15;      // B col -> node offset within tile
  int rg  = l >> 4;      // k-group / C-row group
  int wgid = blockIdx.x * 4 + (tid >> 6);
  int nt = (KCH * N) >> 4;        // row-tiles of 16 (N%16==0 guaranteed by caller)
  int nw = gridDim.x * 4;

  for (int t = wgid; t < nt; t += nw) {
    int row0 = t << 4;                       // row in M = K*N
    int kc = (row0 >= N) ? 1 : 0;            // tiles never straddle kc (N%16==0)
    int n0 = row0 - kc * N;

    // B frags: B[k][col] = x[kc][n0+col][k]; lane reads 32 B contiguous per kstep.
    const float* xb = x + (size_t)(kc * N + n0 + col) * ZF + rg * 8;
    bf16x8_t bhi[4], blo[4];
#pragma unroll
    for (int ks = 0; ks < 4; ++ks) {
      f32x4n u = __builtin_nontemporal_load((const f32x4n*)(xb + ks * 32));
      f32x4n v = __builtin_nontemporal_load(((const f32x4n*)(xb + ks * 32)) + 1);
      float tmp[8] = {u[0], u[1], u[2], u[3], v[0], v[1], v[2], v[3]};
#pragma unroll
      for (int j = 0; j < 8; ++j) {
        u16 hi = f2bf(tmp[j]);
        bhi[ks][j] = (short)hi;
        blo[ks][j] = (short)f2bf(tmp[j] - bf2f(hi));
      }
    }

    f32x4_t acc[8];
#pragma unroll
    for (int ft = 0; ft < 8; ++ft) acc[ft] = {0.f, 0.f, 0.f, 0.f};

#pragma unroll
    for (int ft = 0; ft < 8; ++ft) {
#pragma unroll
      for (int ks = 0; ks < 4; ++ks) {
        int eb = ((ft * 4 + ks) * 64 + l) * 8;
        const bf16x8_t ahi = *(const bf16x8_t*)(lw + eb);           // lane-contiguous,
        const bf16x8_t alo = *(const bf16x8_t*)(lw + 16384 + eb);   // conflict-free b128
        acc[ft] = __builtin_amdgcn_mfma_f32_16x16x32_bf16(ahi, bhi[ks], acc[ft], 0, 0, 0);
        acc[ft] = __builtin_amdgcn_mfma_f32_16x16x32_bf16(alo, bhi[ks], acc[ft], 0, 0, 0);
        acc[ft] = __builtin_amdgcn_mfma_f32_16x16x32_bf16(ahi, blo[ks], acc[ft], 0, 0, 0);
      }
    }

    // C layout: D[row=(l>>4)*4+r][col=l&15]; f = ft*16 + rg*4 + r  -> contiguous ushort4.
    // xi stores stay NORMAL (cached): spmm re-reads xi ~16x.
    u16* dst = xi + (size_t)(n0 + col) * 256 + kc * 128;
#pragma unroll
    for (int ft = 0; ft < 8; ++ft) {
      ushort4 o;
      o.x = f2bf(acc[ft][0]);
      o.y = f2bf(acc[ft][1]);
      o.z = f2bf(acc[ft][2]);
      o.w = f2bf(acc[ft][3]);
      *(ushort4*)(dst + ft * 16 + rg * 4) = o;
    }
  }
}

// ---------- CSR SpMM over bf16 support: one wave per row, fused relu ----------
// out stores are NON-TEMPORAL: out (100 MB, never re-read) otherwise
// write-allocates through L2/L3 and evicts xi (51.2 MB, reused ~16x) --
// suspected source of the 470 MB FETCH (vs ~64 MB compulsory).
__global__ __launch_bounds__(256) void spmm_csr_bf16(
    const u16* __restrict__ xi, const int* __restrict__ row_off,
    const int2* __restrict__ pairs, float* __restrict__ out, int N) {
  int r = blockIdx.x * 4 + (threadIdx.x >> 6);
  int lane = threadIdx.x & 63;
  if (r >= N) return;
  int beg = row_off[r];
  int end = row_off[r + 1];

  float4 acc = make_float4(0.f, 0.f, 0.f, 0.f);
  int j = beg;
  for (; j + 4 <= end; j += 4) {
    int2 p0 = pairs[j + 0];
    int2 p1 = pairs[j + 1];
    int2 p2 = pairs[j + 2];
    int2 p3 = pairs[j + 3];
    ushort4 a0 = ((const ushort4*)(xi + (size_t)p0.x * 256))[lane];
    ushort4 a1 = ((const ushort4*)(xi + (size_t)p1.x * 256))[lane];
    ushort4 a2 = ((const ushort4*)(xi + (size_t)p2.x * 256))[lane];
    ushort4 a3 = ((const ushort4*)(xi + (size_t)p3.x * 256))[lane];
    float v0 = __int_as_float(p0.y);
    float v1 = __int_as_float(p1.y);
    float v2 = __int_as_float(p2.y);
    float v3 = __int_as_float(p3.y);
    acc.x = fmaf(v0, bf2f(a0.x), acc.x);
    acc.y = fmaf(v0, bf2f(a0.y), acc.y);
    acc.z = fmaf(v0, bf2f(a0.z), acc.z);
    acc.w = fmaf(v0, bf2f(a0.w), acc.w);
    acc.x = fmaf(v1, bf2f(a1.x), acc.x);
    acc.y = fmaf(v1, bf2f(a1.y), acc.y);
    acc.z = fmaf(v1, bf2f(a1.z), acc.z);
    acc.w = fmaf(v1, bf2f(a1.w), acc.w);
    acc.x = fmaf(v2, bf2f(a2.x), acc.x);
    acc.y = fmaf(v2, bf2f(a2.y), acc.y);
    acc.z = fmaf(v2, bf2f(a2.z), acc.z);
    acc.w = fmaf(v2, bf2f(a2.w), acc.w);
    acc.x = fmaf(v3, bf2f(a3.x), acc.x);
    acc.y = fmaf(v3, bf2f(a3.y), acc.y);
    acc.z = fmaf(v3, bf2f(a3.z), acc.z);
    acc.w = fmaf(v3, bf2f(a3.w), acc.w);
  }
  for (; j < end; ++j) {
    int2 p = pairs[j];
    ushort4 a = ((const ushort4*)(xi + (size_t)p.x * 256))[lane];
    float v = __int_as_float(p.y);
    acc.x = fmaf(v, bf2f(a.x), acc.x);
    acc.y = fmaf(v, bf2f(a.y), acc.y);
    acc.z = fmaf(v, bf2f(a.z), acc.z);
    acc.w = fmaf(v, bf2f(a.w), acc.w);
  }
  f32x4n o;
  o[0] = fmaxf(acc.x, 0.f);
  o[1] = fmaxf(acc.y, 0.f);
  o[2] = fmaxf(acc.z, 0.f);
  o[3] = fmaxf(acc.w, 0.f);
  int k = lane >> 5;
  int g = lane & 31;
  __builtin_nontemporal_store(o, ((f32x4n*)(out + ((size_t)k * N + (size_t)r) * ZF)) + g);
}

// ---------- mid-tier fallback: fp32 CSR SpMM (A@x, no relu; gemm pass follows) ----------
__global__ __launch_bounds__(256) void spmm_csr(
    const float* __restrict__ x, const int* __restrict__ row_off,
    const int2* __restrict__ pairs, float* __restrict__ out, int N) {
  int r = blockIdx.x * 4 + (threadIdx.x >> 6);
  int lane = threadIdx.x & 63;
  if (r >= N) return;
  int k = lane >> 5;
  int g = lane & 31;
  int beg = row_off[r];
  int end = row_off[r + 1];
  const float* xb = x + (size_t)k * N * ZF;
  float4 acc = make_float4(0.f, 0.f, 0.f, 0.f);
  for (int j = beg; j < end; ++j) {
    int2 p = pairs[j];
    float4 a = ((const float4*)(xb + (size_t)p.x * ZF))[g];
    float v = __int_as_float(p.y);
    acc.x = fmaf(v, a.x, acc.x);
    acc.y = fmaf(v, a.y, acc.y);
    acc.z = fmaf(v, a.z, acc.z);
    acc.w = fmaf(v, a.w, acc.w);
  }
  ((float4*)(out + ((size_t)k * N + (size_t)r) * ZF))[g] = acc;
}

// ---------- last-resort fallback: atomic scatter ----------
__device__ inline void atomic_add_f32(float* p, float v) {
#if defined(__HIP_DEVICE_COMPILE__) && defined(__AMDGCN__)
  unsafeAtomicAdd(p, v);
#else
  atomicAdd(p, v);
#endif
}

__global__ __launch_bounds__(256) void zero_kernel(float4* __restrict__ p, long long n4) {
  long long i = (long long)blockIdx.x * 256 + threadIdx.x;
  long long stride = (long long)gridDim.x * 256;
  for (; i < n4; i += stride) p[i] = make_float4(0.f, 0.f, 0.f, 0.f);
}

__global__ __launch_bounds__(256) void scatter_spmm_kernel(
    const float* __restrict__ x, const int* __restrict__ rows,
    const int* __restrict__ cols, const float* __restrict__ vals,
    float* __restrict__ tmp, int E, int N) {
  int t = blockIdx.x * 256 + threadIdx.x;
  int e = t >> 6;
  if (e >= E) return;
  int sub = t & 63;
  int k = sub >> 5;
  int g = sub & 31;
  int row = rows[e];
  int col = cols[e];
  float val = vals[e];
  const float4* src = (const float4*)(x + ((size_t)k * N + col) * ZF);
  float4 v = src[g];
  float* dst = tmp + ((size_t)k * N + row) * ZF + (size_t)g * 4;
  atomic_add_f32(dst + 0, val * v.x);
  atomic_add_f32(dst + 1, val * v.y);
  atomic_add_f32(dst + 2, val * v.z);
  atomic_add_f32(dst + 3, val * v.w);
}

// ---------- fallback pass 2: io[m,:] = relu(io[m,:] @ W) in place ----------
__global__ __launch_bounds__(256) void gemm_relu_inplace(
    float* __restrict__ io, const float* __restrict__ W, long long Mtotal) {
  __shared__ float Ws[64 * ZF];
  __shared__ float Xs[32 * ZF];
  int tid = threadIdx.x;
  long long row0 = (long long)blockIdx.x * 32;

  const float4* src = (const float4*)(io + row0 * ZF);
  float4* Xs4 = (float4*)Xs;
#pragma unroll
  for (int i = 0; i < 4; ++i) {
    int idx = tid + i * 256;
    long long r = row0 + (idx >> 5);
    Xs4[idx] = (r < Mtotal) ? src[idx] : make_float4(0.f, 0.f, 0.f, 0.f);
  }

  int f0 = (tid & 31) * 4;
  int rg = tid >> 5;

  float acc[4][4];
#pragma unroll
  for (int j = 0; j < 4; ++j)
#pragma unroll
    for (int i = 0; i < 4; ++i) acc[j][i] = 0.f;

  const float4* W4 = (const float4*)W;
  float4* Ws4 = (float4*)Ws;

  for (int zh = 0; zh < 2; ++zh) {
    __syncthreads();
#pragma unroll
    for (int i = 0; i < 8; ++i) {
      int idx = tid + i * 256;
      Ws4[idx] = W4[(size_t)zh * 2048 + idx];
    }
    __syncthreads();

#pragma unroll 4
    for (int z = 0; z < 64; ++z) {
      float4 wv = *(const float4*)(Ws + z * ZF + f0);
#pragma unroll
      for (int j = 0; j < 4; ++j) {
        float xv = Xs[(rg + 8 * j) * ZF + (zh * 64 + z)];
        acc[j][0] = fmaf(xv, wv.x, acc[j][0]);
        acc[j][1] = fmaf(xv, wv.y, acc[j][1]);
        acc[j][2] = fmaf(xv, wv.z, acc[j][2]);
        acc[j][3] = fmaf(xv, wv.w, acc[j][3]);
      }
    }
  }

#pragma unroll
  for (int j = 0; j < 4; ++j) {
    long long r = row0 + rg + 8 * j;
    if (r < Mtotal) {
      float4 o;
      o.x = fmaxf(acc[j][0], 0.f);
      o.y = fmaxf(acc[j][1], 0.f);
      o.z = fmaxf(acc[j][2], 0.f);
      o.w = fmaxf(acc[j][3], 0.f);
      *(float4*)(io + r * ZF + f0) = o;
    }
  }
}

extern "C" void kernel_launch(void* const* d_in, const int* in_sizes, int n_in,
                              void* d_out, int out_size, void* d_ws, size_t ws_size,
                              hipStream_t stream) {
  const float* x    = (const float*)d_in[0];   // [K, N, Z]
  const int*   rows = (const int*)d_in[1];     // [E]
  const int*   cols = (const int*)d_in[2];     // [E]
  const float* vals = (const float*)d_in[3];   // [E]
  const float* W    = (const float*)d_in[4];   // [Z, F]

  int E = in_sizes[1];
  int N = in_sizes[0] / (KCH * ZF);
  float* out = (float*)d_out;

  int nch = (N + CHUNK - 1) / CHUNK;           // 391 for N=100k (must be <= 512)

  size_t off = 0;
  auto carve = [&](size_t bytes) {
    size_t p = off;
    off += (bytes + 15) & ~(size_t)15;
    return (char*)d_ws + p;
  };
  int*  row_off = (int*)carve((size_t)(N + 1) * 4);
  int*  cursor  = (int*)carve((size_t)N * 4);
  int*  chunk   = (int*)carve((size_t)nch * 4);
  int2* pairs   = (int2*)carve((size_t)E * 8);
  size_t off_csr = off;
  u16*  wf      = (u16*)carve(65536);                      // W hi/lo frags (64 KB)
  u16*  xi      = (u16*)carve((size_t)N * KCH * ZF * 2);   // 51.2 MB support (bf16)

  bool csr_ok  = (off_csr <= ws_size) && (nch <= 512);
  bool bf16_ok = (off <= ws_size) && (nch <= 512) && ((N & 15) == 0);

  if (csr_ok) {
    int nb_N = (N + 255) / 256;
    int nb_E = (E + 255) / 256;

    int wblocks = bf16_ok ? 64 : 0;
    zero_and_wfrag<<<nb_N + wblocks, 256, 0, stream>>>(cursor, N, nb_N, W, wf);
    hist_kernel<<<nb_E, 256, 0, stream>>>(rows, cursor, E);
    chunk_reduce<<<nch, 256, 0, stream>>>(cursor, chunk, N);
    chunk_scan<<<1, 512, 0, stream>>>(chunk, nch, row_off, N, E);
    scan_within_chunk<<<nch, 256, 0, stream>>>(cursor, chunk, row_off, cursor, N);
    bucket_kernel<<<nb_E, 256, 0, stream>>>(rows, cols, vals, cursor, pairs, E);

    int sblocks = (N + 3) / 4;
    if (bf16_ok) {
      gemm_xw_bf16<<<512, 256, 0, stream>>>(x, wf, xi, N);
      spmm_csr_bf16<<<sblocks, 256, 0, stream>>>(xi, row_off, pairs, out, N);
    } else {
      spmm_csr<<<sblocks, 256, 0, stream>>>(x, row_off, pairs, out, N);
      long long Mtotal = (long long)KCH * N;
      int mblocks = (int)((Mtotal + 31) / 32);
      gemm_relu_inplace<<<mblocks, 256, 0, stream>>>(out, W, Mtotal);
    }
  } else {
    long long n4 = (long long)out_size / 4;
    int zblocks = (int)((n4 + 255) / 256);
    zero_kernel<<<zblocks, 256, 0, stream>>>((float4*)out, n4);
    long long total_threads = (long long)E * 64;
    int sblocks = (int)((total_threads + 255) / 256);
    scatter_spmm_kernel<<<sblocks, 256, 0, stream>>>(x, rows, cols, vals, out, E, N);
    long long Mtotal = (long long)KCH * N;
    int mblocks = (int)((Mtotal + 31) / 32);
    gemm_relu_inplace<<<mblocks, 256, 0, stream>>>(out, W, Mtotal);
  }
}

// Round 7
// 551.984 us; speedup vs baseline: 1.0193x; 1.0012x over previous
//
#include <hip/hip_runtime.h>

#define KCH 2
#define ZF 128   // Z == F == 128
#define CHUNK 256
typedef unsigned short u16;

using bf16x8_t = __attribute__((ext_vector_type(8))) short;  // MFMA A/B frag (8 bf16)
using f32x4_t  = __attribute__((ext_vector_type(4))) float;  // MFMA C/D frag
using f32x4n   = __attribute__((ext_vector_type(4))) float;  // native vec for nontemporal builtins

// ---------- bf16 helpers ----------
__device__ inline u16 f2bf(float f) {            // round-to-nearest-even
  unsigned u = __float_as_uint(f);
  return (u16)((u + 0x7FFF + ((u >> 16) & 1)) >> 16);
}
__device__ inline float bf2f(u16 h) { return __uint_as_float((unsigned)h << 16); }

// ---------- counting-sort utilities ----------
// zero cursor AND build W fragments in one dispatch (independent work;
// saves a launch gap).  Blocks [0,nbN): zero. Blocks [nbN, nbN+64): wfrag.
__global__ __launch_bounds__(256) void zero_and_wfrag(
    int* __restrict__ p, int n, int nbN,
    const float* __restrict__ W, u16* __restrict__ wf) {
  if ((int)blockIdx.x < nbN) {
    int i = blockIdx.x * 256 + threadIdx.x;
    if (i < n) p[i] = 0;
    return;
  }
  // W -> bf16 hi/lo split, pre-arranged in MFMA A-fragment order.
  // A-frag layout for mfma_f32_16x16x32_bf16: lane l supplies
  // A[row=l&15][k=(l>>4)*8+j], j=0..7 contiguous.  A = W^T tile.
  // Element e = ((ft*4+ks)*64 + l)*8 + j holds W[k][f],
  //   k = ks*32 + (l>>4)*8 + j,  f = ft*16 + (l&15).
  int t = (blockIdx.x - nbN) * 256 + threadIdx.x;   // t = k*128 + f
  if (t >= 16384) return;
  int k = t >> 7, f = t & 127;
  int ks = k >> 5, kk = k & 31;
  int lg = kk >> 3, j = kk & 7;
  int ft = f >> 4, c = f & 15;
  int l = lg * 16 + c;
  int e = ((ft * 4 + ks) * 64 + l) * 8 + j;
  float w = W[t];
  u16 hi = f2bf(w);
  u16 lo = f2bf(w - bf2f(hi));   // exact residual, then RNE
  wf[e] = hi;
  wf[16384 + e] = lo;
}

__global__ __launch_bounds__(256) void hist_kernel(
    const int* __restrict__ rows, int* __restrict__ cnt, int E) {
  int i = blockIdx.x * 256 + threadIdx.x;
  if (i < E) atomicAdd(&cnt[rows[i]], 1);   // 400 KB counter array: L2-resident
}

__global__ __launch_bounds__(256) void chunk_reduce(
    const int* __restrict__ cnt, int* __restrict__ chunk, int N) {
  __shared__ int s[256];
  int tid = threadIdx.x;
  int i = blockIdx.x * 256 + tid;
  s[tid] = (i < N) ? cnt[i] : 0;
  __syncthreads();
#pragma unroll
  for (int o = 128; o > 0; o >>= 1) {
    if (tid < o) s[tid] += s[tid + o];
    __syncthreads();
  }
  if (tid == 0) chunk[blockIdx.x] = s[0];
}

__global__ __launch_bounds__(512) void chunk_scan(
    int* __restrict__ chunk, int nch, int* __restrict__ row_off, int N, int E) {
  __shared__ int s[512];
  int tid = threadIdx.x;
  int v = (tid < nch) ? chunk[tid] : 0;
  s[tid] = v;
  __syncthreads();
#pragma unroll
  for (int o = 1; o < 512; o <<= 1) {
    int t = (tid >= o) ? s[tid - o] : 0;
    __syncthreads();
    s[tid] += t;
    __syncthreads();
  }
  if (tid < nch) chunk[tid] = s[tid] - v;   // exclusive
  if (tid == 0) row_off[N] = E;
}

// Exclusive scan within each 256-chunk; writes row_off AND seeds cursor.
__global__ __launch_bounds__(256) void scan_within_chunk(
    const int* __restrict__ cnt, const int* __restrict__ chunk,
    int* __restrict__ row_off, int* __restrict__ cursor, int N) {
  __shared__ int s[256];
  int tid = threadIdx.x;
  int i = blockIdx.x * 256 + tid;
  int v = (i < N) ? cnt[i] : 0;
  s[tid] = v;
  __syncthreads();
#pragma unroll
  for (int o = 1; o < 256; o <<= 1) {
    int t = (tid >= o) ? s[tid - o] : 0;
    __syncthreads();
    s[tid] += t;
    __syncthreads();
  }
  if (i < N) {
    int start = chunk[blockIdx.x] + s[tid] - v;
    row_off[i] = start;
    cursor[i] = start;
  }
}

// Scatter edges into row-sorted order as packed (col, val) int2 pairs.
__global__ __launch_bounds__(256) void bucket_kernel(
    const int* __restrict__ rows, const int* __restrict__ cols,
    const float* __restrict__ vals, int* __restrict__ cursor,
    int2* __restrict__ pairs, int E) {
  int i = blockIdx.x * 256 + threadIdx.x;
  if (i >= E) return;
  int r = rows[i];
  int p = atomicAdd(&cursor[r], 1);
  int2 pr;
  pr.x = cols[i];
  pr.y = __float_as_int(vals[i]);
  pairs[p] = pr;
}

// ---------- support = x @ W via split-bf16 MFMA, written straight into xi ----------
// xi[node][k][f] bf16, 512 B per node (the spmm gather layout).
// Split GEMM: x_hi*W_hi + x_hi*W_lo + x_lo*W_hi  ->  fp32-accurate support;
// only quantization is the final bf16 store.
// x loads are NON-TEMPORAL (read-once) so x doesn't evict xi from L3.
__global__ __launch_bounds__(256) void gemm_xw_bf16(
    const float* __restrict__ x, const u16* __restrict__ wf,
    u16* __restrict__ xi, int N) {
  __shared__ u16 lw[32768];   // 64 KB: [0..16383]=W_hi frags, [16384..]=W_lo frags
  int tid = threadIdx.x;
  {
    const uint4* src = (const uint4*)wf;
    uint4* dst = (uint4*)lw;
#pragma unroll
    for (int i = 0; i < 16; ++i) dst[tid + i * 256] = src[tid + i * 256];
  }
  __syncthreads();

  int l   = tid & 63;
  int col = l & 15;      // B col -> node offset within tile
  int rg  = l >> 4;      // k-group / C-row group
  int wgid = blockIdx.x * 4 + (tid >> 6);
  int nt = (KCH * N) >> 4;        // row-tiles of 16 (N%16==0 guaranteed by caller)
  int nw = gridDim.x * 4;

  for (int t = wgid; t < nt; t += nw) {
    int row0 = t << 4;                       // row in M = K*N
    int kc = (row0 >= N) ? 1 : 0;            // tiles never straddle kc (N%16==0)
    int n0 = row0 - kc * N;

    // B frags: B[k][col] = x[kc][n0+col][k]; lane reads 32 B contiguous per kstep.
    const float* xb = x + (size_t)(kc * N + n0 + col) * ZF + rg * 8;
    bf16x8_t bhi[4], blo[4];
#pragma unroll
    for (int ks = 0; ks < 4; ++ks) {
      f32x4n u = __builtin_nontemporal_load((const f32x4n*)(xb + ks * 32));
      f32x4n v = __builtin_nontemporal_load(((const f32x4n*)(xb + ks * 32)) + 1);
      float tmp[8] = {u[0], u[1], u[2], u[3], v[0], v[1], v[2], v[3]};
#pragma unroll
      for (int j = 0; j < 8; ++j) {
        u16 hi = f2bf(tmp[j]);
        bhi[ks][j] = (short)hi;
        blo[ks][j] = (short)f2bf(tmp[j] - bf2f(hi));
      }
    }

    f32x4_t acc[8];
#pragma unroll
    for (int ft = 0; ft < 8; ++ft) acc[ft] = {0.f, 0.f, 0.f, 0.f};

#pragma unroll
    for (int ft = 0; ft < 8; ++ft) {
#pragma unroll
      for (int ks = 0; ks < 4; ++ks) {
        int eb = ((ft * 4 + ks) * 64 + l) * 8;
        const bf16x8_t ahi = *(const bf16x8_t*)(lw + eb);           // lane-contiguous,
        const bf16x8_t alo = *(const bf16x8_t*)(lw + 16384 + eb);   // conflict-free b128
        acc[ft] = __builtin_amdgcn_mfma_f32_16x16x32_bf16(ahi, bhi[ks], acc[ft], 0, 0, 0);
        acc[ft] = __builtin_amdgcn_mfma_f32_16x16x32_bf16(alo, bhi[ks], acc[ft], 0, 0, 0);
        acc[ft] = __builtin_amdgcn_mfma_f32_16x16x32_bf16(ahi, blo[ks], acc[ft], 0, 0, 0);
      }
    }

    // C layout: D[row=(l>>4)*4+r][col=l&15]; f = ft*16 + rg*4 + r  -> contiguous ushort4.
    // xi stores stay NORMAL (cached): spmm re-reads xi ~16x.
    u16* dst = xi + (size_t)(n0 + col) * 256 + kc * 128;
#pragma unroll
    for (int ft = 0; ft < 8; ++ft) {
      ushort4 o;
      o.x = f2bf(acc[ft][0]);
      o.y = f2bf(acc[ft][1]);
      o.z = f2bf(acc[ft][2]);
      o.w = f2bf(acc[ft][3]);
      *(ushort4*)(dst + ft * 16 + rg * 4) = o;
    }
  }
}

// ---------- CSR SpMM over bf16 support: one wave per row, fused relu ----------
// Launched as 4 quarter-row dispatches (r0, rcnt): perf-neutral split so the
// profile's top-5 can surface the non-spmm hotspots (spmm at 141us was
// shadowing every other kernel).  out stores non-temporal (write-once).
__global__ __launch_bounds__(256) void spmm_csr_bf16(
    const u16* __restrict__ xi, const int* __restrict__ row_off,
    const int2* __restrict__ pairs, float* __restrict__ out, int N,
    int r0, int rcnt) {
  int rr = blockIdx.x * 4 + (threadIdx.x >> 6);
  if (rr >= rcnt) return;
  int r = r0 + rr;
  if (r >= N) return;
  int lane = threadIdx.x & 63;
  int beg = row_off[r];
  int end = row_off[r + 1];

  float4 acc = make_float4(0.f, 0.f, 0.f, 0.f);
  int j = beg;
  for (; j + 4 <= end; j += 4) {
    int2 p0 = pairs[j + 0];
    int2 p1 = pairs[j + 1];
    int2 p2 = pairs[j + 2];
    int2 p3 = pairs[j + 3];
    ushort4 a0 = ((const ushort4*)(xi + (size_t)p0.x * 256))[lane];
    ushort4 a1 = ((const ushort4*)(xi + (size_t)p1.x * 256))[lane];
    ushort4 a2 = ((const ushort4*)(xi + (size_t)p2.x * 256))[lane];
    ushort4 a3 = ((const ushort4*)(xi + (size_t)p3.x * 256))[lane];
    float v0 = __int_as_float(p0.y);
    float v1 = __int_as_float(p1.y);
    float v2 = __int_as_float(p2.y);
    float v3 = __int_as_float(p3.y);
    acc.x = fmaf(v0, bf2f(a0.x), acc.x);
    acc.y = fmaf(v0, bf2f(a0.y), acc.y);
    acc.z = fmaf(v0, bf2f(a0.z), acc.z);
    acc.w = fmaf(v0, bf2f(a0.w), acc.w);
    acc.x = fmaf(v1, bf2f(a1.x), acc.x);
    acc.y = fmaf(v1, bf2f(a1.y), acc.y);
    acc.z = fmaf(v1, bf2f(a1.z), acc.z);
    acc.w = fmaf(v1, bf2f(a1.w), acc.w);
    acc.x = fmaf(v2, bf2f(a2.x), acc.x);
    acc.y = fmaf(v2, bf2f(a2.y), acc.y);
    acc.z = fmaf(v2, bf2f(a2.z), acc.z);
    acc.w = fmaf(v2, bf2f(a2.w), acc.w);
    acc.x = fmaf(v3, bf2f(a3.x), acc.x);
    acc.y = fmaf(v3, bf2f(a3.y), acc.y);
    acc.z = fmaf(v3, bf2f(a3.z), acc.z);
    acc.w = fmaf(v3, bf2f(a3.w), acc.w);
  }
  for (; j < end; ++j) {
    int2 p = pairs[j];
    ushort4 a = ((const ushort4*)(xi + (size_t)p.x * 256))[lane];
    float v = __int_as_float(p.y);
    acc.x = fmaf(v, bf2f(a.x), acc.x);
    acc.y = fmaf(v, bf2f(a.y), acc.y);
    acc.z = fmaf(v, bf2f(a.z), acc.z);
    acc.w = fmaf(v, bf2f(a.w), acc.w);
  }
  f32x4n o;
  o[0] = fmaxf(acc.x, 0.f);
  o[1] = fmaxf(acc.y, 0.f);
  o[2] = fmaxf(acc.z, 0.f);
  o[3] = fmaxf(acc.w, 0.f);
  int k = lane >> 5;
  int g = lane & 31;
  __builtin_nontemporal_store(o, ((f32x4n*)(out + ((size_t)k * N + (size_t)r) * ZF)) + g);
}

// ---------- mid-tier fallback: fp32 CSR SpMM (A@x, no relu; gemm pass follows) ----------
__global__ __launch_bounds__(256) void spmm_csr(
    const float* __restrict__ x, const int* __restrict__ row_off,
    const int2* __restrict__ pairs, float* __restrict__ out, int N) {
  int r = blockIdx.x * 4 + (threadIdx.x >> 6);
  int lane = threadIdx.x & 63;
  if (r >= N) return;
  int k = lane >> 5;
  int g = lane & 31;
  int beg = row_off[r];
  int end = row_off[r + 1];
  const float* xb = x + (size_t)k * N * ZF;
  float4 acc = make_float4(0.f, 0.f, 0.f, 0.f);
  for (int j = beg; j < end; ++j) {
    int2 p = pairs[j];
    float4 a = ((const float4*)(xb + (size_t)p.x * ZF))[g];
    float v = __int_as_float(p.y);
    acc.x = fmaf(v, a.x, acc.x);
    acc.y = fmaf(v, a.y, acc.y);
    acc.z = fmaf(v, a.z, acc.z);
    acc.w = fmaf(v, a.w, acc.w);
  }
  ((float4*)(out + ((size_t)k * N + (size_t)r) * ZF))[g] = acc;
}

// ---------- last-resort fallback: atomic scatter ----------
__device__ inline void atomic_add_f32(float* p, float v) {
#if defined(__HIP_DEVICE_COMPILE__) && defined(__AMDGCN__)
  unsafeAtomicAdd(p, v);
#else
  atomicAdd(p, v);
#endif
}

__global__ __launch_bounds__(256) void zero_kernel(float4* __restrict__ p, long long n4) {
  long long i = (long long)blockIdx.x * 256 + threadIdx.x;
  long long stride = (long long)gridDim.x * 256;
  for (; i < n4; i += stride) p[i] = make_float4(0.f, 0.f, 0.f, 0.f);
}

__global__ __launch_bounds__(256) void scatter_spmm_kernel(
    const float* __restrict__ x, const int* __restrict__ rows,
    const int* __restrict__ cols, const float* __restrict__ vals,
    float* __restrict__ tmp, int E, int N) {
  int t = blockIdx.x * 256 + threadIdx.x;
  int e = t >> 6;
  if (e >= E) return;
  int sub = t & 63;
  int k = sub >> 5;
  int g = sub & 31;
  int row = rows[e];
  int col = cols[e];
  float val = vals[e];
  const float4* src = (const float4*)(x + ((size_t)k * N + col) * ZF);
  float4 v = src[g];
  float* dst = tmp + ((size_t)k * N + row) * ZF + (size_t)g * 4;
  atomic_add_f32(dst + 0, val * v.x);
  atomic_add_f32(dst + 1, val * v.y);
  atomic_add_f32(dst + 2, val * v.z);
  atomic_add_f32(dst + 3, val * v.w);
}

// ---------- fallback pass 2: io[m,:] = relu(io[m,:] @ W) in place ----------
__global__ __launch_bounds__(256) void gemm_relu_inplace(
    float* __restrict__ io, const float* __restrict__ W, long long Mtotal) {
  __shared__ float Ws[64 * ZF];
  __shared__ float Xs[32 * ZF];
  int tid = threadIdx.x;
  long long row0 = (long long)blockIdx.x * 32;

  const float4* src = (const float4*)(io + row0 * ZF);
  float4* Xs4 = (float4*)Xs;
#pragma unroll
  for (int i = 0; i < 4; ++i) {
    int idx = tid + i * 256;
    long long r = row0 + (idx >> 5);
    Xs4[idx] = (r < Mtotal) ? src[idx] : make_float4(0.f, 0.f, 0.f, 0.f);
  }

  int f0 = (tid & 31) * 4;
  int rg = tid >> 5;

  float acc[4][4];
#pragma unroll
  for (int j = 0; j < 4; ++j)
#pragma unroll
    for (int i = 0; i < 4; ++i) acc[j][i] = 0.f;

  const float4* W4 = (const float4*)W;
  float4* Ws4 = (float4*)Ws;

  for (int zh = 0; zh < 2; ++zh) {
    __syncthreads();
#pragma unroll
    for (int i = 0; i < 8; ++i) {
      int idx = tid + i * 256;
      Ws4[idx] = W4[(size_t)zh * 2048 + idx];
    }
    __syncthreads();

#pragma unroll 4
    for (int z = 0; z < 64; ++z) {
      float4 wv = *(const float4*)(Ws + z * ZF + f0);
#pragma unroll
      for (int j = 0; j < 4; ++j) {
        float xv = Xs[(rg + 8 * j) * ZF + (zh * 64 + z)];
        acc[j][0] = fmaf(xv, wv.x, acc[j][0]);
        acc[j][1] = fmaf(xv, wv.y, acc[j][1]);
        acc[j][2] = fmaf(xv, wv.z, acc[j][2]);
        acc[j][3] = fmaf(xv, wv.w, acc[j][3]);
      }
    }
  }

#pragma unroll
  for (int j = 0; j < 4; ++j) {
    long long r = row0 + rg + 8 * j;
    if (r < Mtotal) {
      float4 o;
      o.x = fmaxf(acc[j][0], 0.f);
      o.y = fmaxf(acc[j][1], 0.f);
      o.z = fmaxf(acc[j][2], 0.f);
      o.w = fmaxf(acc[j][3], 0.f);
      *(float4*)(io + r * ZF + f0) = o;
    }
  }
}

extern "C" void kernel_launch(void* const* d_in, const int* in_sizes, int n_in,
                              void* d_out, int out_size, void* d_ws, size_t ws_size,
                              hipStream_t stream) {
  const float* x    = (const float*)d_in[0];   // [K, N, Z]
  const int*   rows = (const int*)d_in[1];     // [E]
  const int*   cols = (const int*)d_in[2];     // [E]
  const float* vals = (const float*)d_in[3];   // [E]
  const float* W    = (const float*)d_in[4];   // [Z, F]

  int E = in_sizes[1];
  int N = in_sizes[0] / (KCH * ZF);
  float* out = (float*)d_out;

  int nch = (N + CHUNK - 1) / CHUNK;           // 391 for N=100k (must be <= 512)

  size_t off = 0;
  auto carve = [&](size_t bytes) {
    size_t p = off;
    off += (bytes + 15) & ~(size_t)15;
    return (char*)d_ws + p;
  };
  int*  row_off = (int*)carve((size_t)(N + 1) * 4);
  int*  cursor  = (int*)carve((size_t)N * 4);
  int*  chunk   = (int*)carve((size_t)nch * 4);
  int2* pairs   = (int2*)carve((size_t)E * 8);
  size_t off_csr = off;
  u16*  wf      = (u16*)carve(65536);                      // W hi/lo frags (64 KB)
  u16*  xi      = (u16*)carve((size_t)N * KCH * ZF * 2);   // 51.2 MB support (bf16)

  bool csr_ok  = (off_csr <= ws_size) && (nch <= 512);
  bool bf16_ok = (off <= ws_size) && (nch <= 512) && ((N & 15) == 0);

  if (csr_ok) {
    int nb_N = (N + 255) / 256;
    int nb_E = (E + 255) / 256;

    int wblocks = bf16_ok ? 64 : 0;
    zero_and_wfrag<<<nb_N + wblocks, 256, 0, stream>>>(cursor, N, nb_N, W, wf);
    hist_kernel<<<nb_E, 256, 0, stream>>>(rows, cursor, E);
    chunk_reduce<<<nch, 256, 0, stream>>>(cursor, chunk, N);
    chunk_scan<<<1, 512, 0, stream>>>(chunk, nch, row_off, N, E);
    scan_within_chunk<<<nch, 256, 0, stream>>>(cursor, chunk, row_off, cursor, N);
    bucket_kernel<<<nb_E, 256, 0, stream>>>(rows, cols, vals, cursor, pairs, E);

    if (bf16_ok) {
      gemm_xw_bf16<<<512, 256, 0, stream>>>(x, wf, xi, N);
      // 4 quarter-row dispatches (visibility split; same total work)
      int q = (N + 3) / 4;
      for (int i = 0; i < 4; ++i) {
        int r0 = i * q;
        int rcnt = (r0 + q <= N) ? q : (N - r0);
        if (rcnt <= 0) break;
        int blocks = (rcnt + 3) / 4;
        spmm_csr_bf16<<<blocks, 256, 0, stream>>>(xi, row_off, pairs, out, N, r0, rcnt);
      }
    } else {
      int sblocks = (N + 3) / 4;
      spmm_csr<<<sblocks, 256, 0, stream>>>(x, row_off, pairs, out, N);
      long long Mtotal = (long long)KCH * N;
      int mblocks = (int)((Mtotal + 31) / 32);
      gemm_relu_inplace<<<mblocks, 256, 0, stream>>>(out, W, Mtotal);
    }
  } else {
    long long n4 = (long long)out_size / 4;
    int zblocks = (int)((n4 + 255) / 256);
    zero_kernel<<<zblocks, 256, 0, stream>>>((float4*)out, n4);
    long long total_threads = (long long)E * 64;
    int sblocks = (int)((total_threads + 255) / 256);
    scatter_spmm_kernel<<<sblocks, 256, 0, stream>>>(x, rows, cols, vals, out, E, N);
    long long Mtotal = (long long)KCH * N;
    int mblocks = (int)((Mtotal + 31) / 32);
    gemm_relu_inplace<<<mblocks, 256, 0, stream>>>(out, W, Mtotal);
  }
}

// Round 8
// 468.028 us; speedup vs baseline: 1.2021x; 1.1794x over previous
//
#include <hip/hip_runtime.h>

#define KCH 2
#define ZF 128   // Z == F == 128
#define CHUNK 256
#define BSH 9    // coarse bucket = 512 rows
typedef unsigned short u16;

using bf16x8_t = __attribute__((ext_vector_type(8))) short;  // MFMA A/B frag (8 bf16)
using f32x4_t  = __attribute__((ext_vector_type(4))) float;  // MFMA C/D frag
using f32x4n   = __attribute__((ext_vector_type(4))) float;  // native vec for nontemporal builtins

// ---------- bf16 helpers ----------
__device__ inline u16 f2bf(float f) {            // round-to-nearest-even
  unsigned u = __float_as_uint(f);
  return (u16)((u + 0x7FFF + ((u >> 16) & 1)) >> 16);
}
__device__ inline float bf2f(u16 h) { return __uint_as_float((unsigned)h << 16); }

// ---------- shared prep: zero counters + build W fragments ----------
// Blocks [0,nbN): zero p[0..n). Blocks [nbN, nbN+64): wfrag.
__global__ __launch_bounds__(256) void zero_and_wfrag(
    int* __restrict__ p, int n, int nbN,
    const float* __restrict__ W, u16* __restrict__ wf) {
  if ((int)blockIdx.x < nbN) {
    int i = blockIdx.x * 256 + threadIdx.x;
    if (i < n) p[i] = 0;
    return;
  }
  // W -> bf16 hi/lo split in MFMA A-fragment order (see r2 notes).
  int t = (blockIdx.x - nbN) * 256 + threadIdx.x;   // t = k*128 + f
  if (t >= 16384) return;
  int k = t >> 7, f = t & 127;
  int ks = k >> 5, kk = k & 31;
  int lg = kk >> 3, j = kk & 7;
  int ft = f >> 4, c = f & 15;
  int l = lg * 16 + c;
  int e = ((ft * 4 + ks) * 64 + l) * 8 + j;
  float w = W[t];
  u16 hi = f2bf(w);
  u16 lo = f2bf(w - bf2f(hi));   // exact residual, then RNE
  wf[e] = hi;
  wf[16384 + e] = lo;
}

// =================== NEW two-level binned sort ===================
// cw layout (ints): [0..256)=gcnt, [256..512)=gcursor, [512..768]=bbase

__global__ __launch_bounds__(256) void coarse_hist(
    const int* __restrict__ rows, int* __restrict__ gcnt,
    int E, int chunk, int NB) {
  __shared__ int lc[256];
  int t = threadIdx.x;
  lc[t] = 0;
  __syncthreads();
  int b0 = blockIdx.x * chunk;
  int b1 = min(E, b0 + chunk);
  for (int i = b0 + t; i < b1; i += 256)
    atomicAdd(&lc[rows[i] >> BSH], 1);
  __syncthreads();
  if (t < NB && lc[t]) atomicAdd(&gcnt[t], lc[t]);
}

__global__ __launch_bounds__(256) void bucket_scan(
    int* __restrict__ cw, int NB, int E, int* __restrict__ row_off, int N) {
  __shared__ int s[256];
  int t = threadIdx.x;
  int v = (t < NB) ? cw[t] : 0;
  s[t] = v;
  __syncthreads();
#pragma unroll
  for (int o = 1; o < 256; o <<= 1) {
    int u = (t >= o) ? s[t - o] : 0;
    __syncthreads();
    s[t] += u;
    __syncthreads();
  }
  int ex = s[t] - v;               // exclusive prefix
  if (t < NB) { cw[256 + t] = ex; cw[512 + t] = ex; }
  if (t == 0) { cw[512 + NB] = E; row_off[N] = E; }
}

// Scatter edges into coarse buckets with per-block reservation: writes to
// each bucket are contiguous bursts -> write-allocate lines get fully
// written by one block (vs 8x amplification of the random scatter).
__global__ __launch_bounds__(256) void coarse_scatter(
    const int* __restrict__ rows, const int* __restrict__ cols,
    const float* __restrict__ vals, int* __restrict__ gcursor,
    int2* __restrict__ binned_rc, float* __restrict__ binned_v,
    int E, int chunk, int NB) {
  __shared__ int lc[256];
  __shared__ int lcur[256];
  int t = threadIdx.x;
  lc[t] = 0;
  __syncthreads();
  int b0 = blockIdx.x * chunk;
  int b1 = min(E, b0 + chunk);
  for (int i = b0 + t; i < b1; i += 256)
    atomicAdd(&lc[rows[i] >> BSH], 1);
  __syncthreads();
  if (t < NB) lcur[t] = lc[t] ? atomicAdd(&gcursor[t], lc[t]) : 0;
  __syncthreads();
  for (int i = b0 + t; i < b1; i += 256) {
    int r = rows[i];
    int p = atomicAdd(&lcur[r >> BSH], 1);
    binned_rc[p] = make_int2(r, cols[i]);
    binned_v[p] = vals[i];
  }
}

// One block per coarse bucket: fine counting sort of ~8K edges over 512
// rows entirely in LDS; scatter destination is a ~65KB contiguous window
// owned by this CU -> full-line writebacks, no amplification.  Also emits
// row_off for its row range (coalesced).
__global__ __launch_bounds__(256) void fine_sort(
    const int2* __restrict__ binned_rc, const float* __restrict__ binned_v,
    const int* __restrict__ bbase, int2* __restrict__ pairs,
    int* __restrict__ row_off, int N) {
  int b = blockIdx.x;
  int beg = bbase[b];
  int endb = bbase[b + 1];
  int row0 = b << BSH;
  int nr = min(1 << BSH, N - row0);
  __shared__ int cnt[512];
  __shared__ int s2[256];
  __shared__ int cur[512];
  int t = threadIdx.x;
  cnt[t] = 0;
  cnt[t + 256] = 0;
  __syncthreads();
  for (int i = beg + t; i < endb; i += 256)
    atomicAdd(&cnt[binned_rc[i].x - row0], 1);
  __syncthreads();
  int c0 = cnt[2 * t], c1 = cnt[2 * t + 1];
  s2[t] = c0 + c1;
  __syncthreads();
#pragma unroll
  for (int o = 1; o < 256; o <<= 1) {
    int u = (t >= o) ? s2[t - o] : 0;
    __syncthreads();
    s2[t] += u;
    __syncthreads();
  }
  int exb = s2[t] - (c0 + c1);     // exclusive prefix of element 2t
  cur[2 * t] = beg + exb;
  cur[2 * t + 1] = beg + exb + c0;
  if (2 * t < nr)     row_off[row0 + 2 * t]     = beg + exb;
  if (2 * t + 1 < nr) row_off[row0 + 2 * t + 1] = beg + exb + c0;
  __syncthreads();
  for (int i = beg + t; i < endb; i += 256) {
    int2 rc = binned_rc[i];
    float v = binned_v[i];
    int p = atomicAdd(&cur[rc.x - row0], 1);
    pairs[p] = make_int2(rc.y, __float_as_int(v));
  }
}

// =================== legacy prep chain (fallback) ===================
__global__ __launch_bounds__(256) void hist_kernel(
    const int* __restrict__ rows, int* __restrict__ cnt, int E) {
  int i = blockIdx.x * 256 + threadIdx.x;
  if (i < E) atomicAdd(&cnt[rows[i]], 1);
}

__global__ __launch_bounds__(256) void chunk_reduce(
    const int* __restrict__ cnt, int* __restrict__ chunk, int N) {
  __shared__ int s[256];
  int tid = threadIdx.x;
  int i = blockIdx.x * 256 + tid;
  s[tid] = (i < N) ? cnt[i] : 0;
  __syncthreads();
#pragma unroll
  for (int o = 128; o > 0; o >>= 1) {
    if (tid < o) s[tid] += s[tid + o];
    __syncthreads();
  }
  if (tid == 0) chunk[blockIdx.x] = s[0];
}

__global__ __launch_bounds__(512) void chunk_scan(
    int* __restrict__ chunk, int nch, int* __restrict__ row_off, int N, int E) {
  __shared__ int s[512];
  int tid = threadIdx.x;
  int v = (tid < nch) ? chunk[tid] : 0;
  s[tid] = v;
  __syncthreads();
#pragma unroll
  for (int o = 1; o < 512; o <<= 1) {
    int t = (tid >= o) ? s[tid - o] : 0;
    __syncthreads();
    s[tid] += t;
    __syncthreads();
  }
  if (tid < nch) chunk[tid] = s[tid] - v;
  if (tid == 0) row_off[N] = E;
}

__global__ __launch_bounds__(256) void scan_within_chunk(
    const int* __restrict__ cnt, const int* __restrict__ chunk,
    int* __restrict__ row_off, int* __restrict__ cursor, int N) {
  __shared__ int s[256];
  int tid = threadIdx.x;
  int i = blockIdx.x * 256 + tid;
  int v = (i < N) ? cnt[i] : 0;
  s[tid] = v;
  __syncthreads();
#pragma unroll
  for (int o = 1; o < 256; o <<= 1) {
    int t = (tid >= o) ? s[tid - o] : 0;
    __syncthreads();
    s[tid] += t;
    __syncthreads();
  }
  if (i < N) {
    int start = chunk[blockIdx.x] + s[tid] - v;
    row_off[i] = start;
    cursor[i] = start;
  }
}

__global__ __launch_bounds__(256) void bucket_kernel(
    const int* __restrict__ rows, const int* __restrict__ cols,
    const float* __restrict__ vals, int* __restrict__ cursor,
    int2* __restrict__ pairs, int E) {
  int i = blockIdx.x * 256 + threadIdx.x;
  if (i >= E) return;
  int r = rows[i];
  int p = atomicAdd(&cursor[r], 1);
  int2 pr;
  pr.x = cols[i];
  pr.y = __float_as_int(vals[i]);
  pairs[p] = pr;
}

// ---------- support = x @ W via split-bf16 MFMA, written straight into xi ----------
__global__ __launch_bounds__(256) void gemm_xw_bf16(
    const float* __restrict__ x, const u16* __restrict__ wf,
    u16* __restrict__ xi, int N) {
  __shared__ u16 lw[32768];   // 64 KB: [0..16383]=W_hi frags, [16384..]=W_lo frags
  int tid = threadIdx.x;
  {
    const uint4* src = (const uint4*)wf;
    uint4* dst = (uint4*)lw;
#pragma unroll
    for (int i = 0; i < 16; ++i) dst[tid + i * 256] = src[tid + i * 256];
  }
  __syncthreads();

  int l   = tid & 63;
  int col = l & 15;
  int rg  = l >> 4;
  int wgid = blockIdx.x * 4 + (tid >> 6);
  int nt = (KCH * N) >> 4;
  int nw = gridDim.x * 4;

  for (int t = wgid; t < nt; t += nw) {
    int row0 = t << 4;
    int kc = (row0 >= N) ? 1 : 0;
    int n0 = row0 - kc * N;

    const float* xb = x + (size_t)(kc * N + n0 + col) * ZF + rg * 8;
    bf16x8_t bhi[4], blo[4];
#pragma unroll
    for (int ks = 0; ks < 4; ++ks) {
      f32x4n u = __builtin_nontemporal_load((const f32x4n*)(xb + ks * 32));
      f32x4n v = __builtin_nontemporal_load(((const f32x4n*)(xb + ks * 32)) + 1);
      float tmp[8] = {u[0], u[1], u[2], u[3], v[0], v[1], v[2], v[3]};
#pragma unroll
      for (int j = 0; j < 8; ++j) {
        u16 hi = f2bf(tmp[j]);
        bhi[ks][j] = (short)hi;
        blo[ks][j] = (short)f2bf(tmp[j] - bf2f(hi));
      }
    }

    f32x4_t acc[8];
#pragma unroll
    for (int ft = 0; ft < 8; ++ft) acc[ft] = {0.f, 0.f, 0.f, 0.f};

#pragma unroll
    for (int ft = 0; ft < 8; ++ft) {
#pragma unroll
      for (int ks = 0; ks < 4; ++ks) {
        int eb = ((ft * 4 + ks) * 64 + l) * 8;
        const bf16x8_t ahi = *(const bf16x8_t*)(lw + eb);
        const bf16x8_t alo = *(const bf16x8_t*)(lw + 16384 + eb);
        acc[ft] = __builtin_amdgcn_mfma_f32_16x16x32_bf16(ahi, bhi[ks], acc[ft], 0, 0, 0);
        acc[ft] = __builtin_amdgcn_mfma_f32_16x16x32_bf16(alo, bhi[ks], acc[ft], 0, 0, 0);
        acc[ft] = __builtin_amdgcn_mfma_f32_16x16x32_bf16(ahi, blo[ks], acc[ft], 0, 0, 0);
      }
    }

    u16* dst = xi + (size_t)(n0 + col) * 256 + kc * 128;
#pragma unroll
    for (int ft = 0; ft < 8; ++ft) {
      ushort4 o;
      o.x = f2bf(acc[ft][0]);
      o.y = f2bf(acc[ft][1]);
      o.z = f2bf(acc[ft][2]);
      o.w = f2bf(acc[ft][3]);
      *(ushort4*)(dst + ft * 16 + rg * 4) = o;
    }
  }
}

// ---------- CSR SpMM over bf16 support: one wave per row, fused relu ----------
__global__ __launch_bounds__(256) void spmm_csr_bf16(
    const u16* __restrict__ xi, const int* __restrict__ row_off,
    const int2* __restrict__ pairs, float* __restrict__ out, int N,
    int r0, int rcnt) {
  int rr = blockIdx.x * 4 + (threadIdx.x >> 6);
  if (rr >= rcnt) return;
  int r = r0 + rr;
  if (r >= N) return;
  int lane = threadIdx.x & 63;
  int beg = row_off[r];
  int end = row_off[r + 1];

  float4 acc = make_float4(0.f, 0.f, 0.f, 0.f);
  int j = beg;
  for (; j + 4 <= end; j += 4) {
    int2 p0 = pairs[j + 0];
    int2 p1 = pairs[j + 1];
    int2 p2 = pairs[j + 2];
    int2 p3 = pairs[j + 3];
    ushort4 a0 = ((const ushort4*)(xi + (size_t)p0.x * 256))[lane];
    ushort4 a1 = ((const ushort4*)(xi + (size_t)p1.x * 256))[lane];
    ushort4 a2 = ((const ushort4*)(xi + (size_t)p2.x * 256))[lane];
    ushort4 a3 = ((const ushort4*)(xi + (size_t)p3.x * 256))[lane];
    float v0 = __int_as_float(p0.y);
    float v1 = __int_as_float(p1.y);
    float v2 = __int_as_float(p2.y);
    float v3 = __int_as_float(p3.y);
    acc.x = fmaf(v0, bf2f(a0.x), acc.x);
    acc.y = fmaf(v0, bf2f(a0.y), acc.y);
    acc.z = fmaf(v0, bf2f(a0.z), acc.z);
    acc.w = fmaf(v0, bf2f(a0.w), acc.w);
    acc.x = fmaf(v1, bf2f(a1.x), acc.x);
    acc.y = fmaf(v1, bf2f(a1.y), acc.y);
    acc.z = fmaf(v1, bf2f(a1.z), acc.z);
    acc.w = fmaf(v1, bf2f(a1.w), acc.w);
    acc.x = fmaf(v2, bf2f(a2.x), acc.x);
    acc.y = fmaf(v2, bf2f(a2.y), acc.y);
    acc.z = fmaf(v2, bf2f(a2.z), acc.z);
    acc.w = fmaf(v2, bf2f(a2.w), acc.w);
    acc.x = fmaf(v3, bf2f(a3.x), acc.x);
    acc.y = fmaf(v3, bf2f(a3.y), acc.y);
    acc.z = fmaf(v3, bf2f(a3.z), acc.z);
    acc.w = fmaf(v3, bf2f(a3.w), acc.w);
  }
  for (; j < end; ++j) {
    int2 p = pairs[j];
    ushort4 a = ((const ushort4*)(xi + (size_t)p.x * 256))[lane];
    float v = __int_as_float(p.y);
    acc.x = fmaf(v, bf2f(a.x), acc.x);
    acc.y = fmaf(v, bf2f(a.y), acc.y);
    acc.z = fmaf(v, bf2f(a.z), acc.z);
    acc.w = fmaf(v, bf2f(a.w), acc.w);
  }
  f32x4n o;
  o[0] = fmaxf(acc.x, 0.f);
  o[1] = fmaxf(acc.y, 0.f);
  o[2] = fmaxf(acc.z, 0.f);
  o[3] = fmaxf(acc.w, 0.f);
  int k = lane >> 5;
  int g = lane & 31;
  __builtin_nontemporal_store(o, ((f32x4n*)(out + ((size_t)k * N + (size_t)r) * ZF)) + g);
}

// ---------- mid-tier fallback: fp32 CSR SpMM ----------
__global__ __launch_bounds__(256) void spmm_csr(
    const float* __restrict__ x, const int* __restrict__ row_off,
    const int2* __restrict__ pairs, float* __restrict__ out, int N) {
  int r = blockIdx.x * 4 + (threadIdx.x >> 6);
  int lane = threadIdx.x & 63;
  if (r >= N) return;
  int k = lane >> 5;
  int g = lane & 31;
  int beg = row_off[r];
  int end = row_off[r + 1];
  const float* xb = x + (size_t)k * N * ZF;
  float4 acc = make_float4(0.f, 0.f, 0.f, 0.f);
  for (int j = beg; j < end; ++j) {
    int2 p = pairs[j];
    float4 a = ((const float4*)(xb + (size_t)p.x * ZF))[g];
    float v = __int_as_float(p.y);
    acc.x = fmaf(v, a.x, acc.x);
    acc.y = fmaf(v, a.y, acc.y);
    acc.z = fmaf(v, a.z, acc.z);
    acc.w = fmaf(v, a.w, acc.w);
  }
  ((float4*)(out + ((size_t)k * N + (size_t)r) * ZF))[g] = acc;
}

// ---------- last-resort fallback: atomic scatter ----------
__device__ inline void atomic_add_f32(float* p, float v) {
#if defined(__HIP_DEVICE_COMPILE__) && defined(__AMDGCN__)
  unsafeAtomicAdd(p, v);
#else
  atomicAdd(p, v);
#endif
}

__global__ __launch_bounds__(256) void zero_kernel(float4* __restrict__ p, long long n4) {
  long long i = (long long)blockIdx.x * 256 + threadIdx.x;
  long long stride = (long long)gridDim.x * 256;
  for (; i < n4; i += stride) p[i] = make_float4(0.f, 0.f, 0.f, 0.f);
}

__global__ __launch_bounds__(256) void scatter_spmm_kernel(
    const float* __restrict__ x, const int* __restrict__ rows,
    const int* __restrict__ cols, const float* __restrict__ vals,
    float* __restrict__ tmp, int E, int N) {
  int t = blockIdx.x * 256 + threadIdx.x;
  int e = t >> 6;
  if (e >= E) return;
  int sub = t & 63;
  int k = sub >> 5;
  int g = sub & 31;
  int row = rows[e];
  int col = cols[e];
  float val = vals[e];
  const float4* src = (const float4*)(x + ((size_t)k * N + col) * ZF);
  float4 v = src[g];
  float* dst = tmp + ((size_t)k * N + row) * ZF + (size_t)g * 4;
  atomic_add_f32(dst + 0, val * v.x);
  atomic_add_f32(dst + 1, val * v.y);
  atomic_add_f32(dst + 2, val * v.z);
  atomic_add_f32(dst + 3, val * v.w);
}

// ---------- fallback pass 2: io[m,:] = relu(io[m,:] @ W) in place ----------
__global__ __launch_bounds__(256) void gemm_relu_inplace(
    float* __restrict__ io, const float* __restrict__ W, long long Mtotal) {
  __shared__ float Ws[64 * ZF];
  __shared__ float Xs[32 * ZF];
  int tid = threadIdx.x;
  long long row0 = (long long)blockIdx.x * 32;

  const float4* src = (const float4*)(io + row0 * ZF);
  float4* Xs4 = (float4*)Xs;
#pragma unroll
  for (int i = 0; i < 4; ++i) {
    int idx = tid + i * 256;
    long long r = row0 + (idx >> 5);
    Xs4[idx] = (r < Mtotal) ? src[idx] : make_float4(0.f, 0.f, 0.f, 0.f);
  }

  int f0 = (tid & 31) * 4;
  int rg = tid >> 5;

  float acc[4][4];
#pragma unroll
  for (int j = 0; j < 4; ++j)
#pragma unroll
    for (int i = 0; i < 4; ++i) acc[j][i] = 0.f;

  const float4* W4 = (const float4*)W;
  float4* Ws4 = (float4*)Ws;

  for (int zh = 0; zh < 2; ++zh) {
    __syncthreads();
#pragma unroll
    for (int i = 0; i < 8; ++i) {
      int idx = tid + i * 256;
      Ws4[idx] = W4[(size_t)zh * 2048 + idx];
    }
    __syncthreads();

#pragma unroll 4
    for (int z = 0; z < 64; ++z) {
      float4 wv = *(const float4*)(Ws + z * ZF + f0);
#pragma unroll
      for (int j = 0; j < 4; ++j) {
        float xv = Xs[(rg + 8 * j) * ZF + (zh * 64 + z)];
        acc[j][0] = fmaf(xv, wv.x, acc[j][0]);
        acc[j][1] = fmaf(xv, wv.y, acc[j][1]);
        acc[j][2] = fmaf(xv, wv.z, acc[j][2]);
        acc[j][3] = fmaf(xv, wv.w, acc[j][3]);
      }
    }
  }

#pragma unroll
  for (int j = 0; j < 4; ++j) {
    long long r = row0 + rg + 8 * j;
    if (r < Mtotal) {
      float4 o;
      o.x = fmaxf(acc[j][0], 0.f);
      o.y = fmaxf(acc[j][1], 0.f);
      o.z = fmaxf(acc[j][2], 0.f);
      o.w = fmaxf(acc[j][3], 0.f);
      *(float4*)(io + r * ZF + f0) = o;
    }
  }
}

extern "C" void kernel_launch(void* const* d_in, const int* in_sizes, int n_in,
                              void* d_out, int out_size, void* d_ws, size_t ws_size,
                              hipStream_t stream) {
  const float* x    = (const float*)d_in[0];   // [K, N, Z]
  const int*   rows = (const int*)d_in[1];     // [E]
  const int*   cols = (const int*)d_in[2];     // [E]
  const float* vals = (const float*)d_in[3];   // [E]
  const float* W    = (const float*)d_in[4];   // [Z, F]

  int E = in_sizes[1];
  int N = in_sizes[0] / (KCH * ZF);
  float* out = (float*)d_out;

  int nch = (N + CHUNK - 1) / CHUNK;

  size_t off = 0;
  auto carve = [&](size_t bytes) {
    size_t p = off;
    off += (bytes + 15) & ~(size_t)15;
    return (char*)d_ws + p;
  };
  int*  row_off = (int*)carve((size_t)(N + 1) * 4);
  int*  cursor  = (int*)carve((size_t)N * 4);      // also hosts cw[768+] for binned path
  int*  chunk   = (int*)carve((size_t)nch * 4);
  int2* pairs   = (int2*)carve((size_t)E * 8);
  size_t off_csr = off;
  u16*  wf      = (u16*)carve(65536);              // W hi/lo frags (64 KB)
  u16*  xi      = (u16*)carve((size_t)N * KCH * ZF * 2);   // 51.2 MB support (bf16)

  bool csr_ok  = (off_csr <= ws_size) && (nch <= 512);
  bool bf16_ok = (off <= ws_size) && (nch <= 512) && ((N & 15) == 0);

  int NB = (N + (1 << BSH) - 1) >> BSH;            // coarse buckets (512 rows)
  // binned arrays alias xi (dead before gemm writes xi; stream-ordered)
  bool binned_ok = bf16_ok && (NB <= 256) && (N >= 1024) &&
                   ((size_t)E * 12 <= (size_t)N * KCH * ZF * 2);

  if (csr_ok) {
    int nb_E = (E + 255) / 256;

    if (binned_ok) {
      int2*  binned_rc = (int2*)xi;
      float* binned_v  = (float*)((char*)xi + (size_t)E * 8);
      int*   cw        = cursor;                   // gcnt / gcursor / bbase
      int GA = 512;
      int chunkE = (E + GA - 1) / GA;

      zero_and_wfrag<<<1 + 64, 256, 0, stream>>>(cw, 256, 1, W, wf);
      coarse_hist<<<GA, 256, 0, stream>>>(rows, cw, E, chunkE, NB);
      bucket_scan<<<1, 256, 0, stream>>>(cw, NB, E, row_off, N);
      coarse_scatter<<<GA, 256, 0, stream>>>(rows, cols, vals, cw + 256,
                                             binned_rc, binned_v, E, chunkE, NB);
      fine_sort<<<NB, 256, 0, stream>>>(binned_rc, binned_v, cw + 512,
                                        pairs, row_off, N);
      gemm_xw_bf16<<<512, 256, 0, stream>>>(x, wf, xi, N);
      int sblocks = (N + 3) / 4;
      spmm_csr_bf16<<<sblocks, 256, 0, stream>>>(xi, row_off, pairs, out, N, 0, N);
    } else {
      int nb_N = (N + 255) / 256;
      int wblocks = bf16_ok ? 64 : 0;
      zero_and_wfrag<<<nb_N + wblocks, 256, 0, stream>>>(cursor, N, nb_N, W, wf);
      hist_kernel<<<nb_E, 256, 0, stream>>>(rows, cursor, E);
      chunk_reduce<<<nch, 256, 0, stream>>>(cursor, chunk, N);
      chunk_scan<<<1, 512, 0, stream>>>(chunk, nch, row_off, N, E);
      scan_within_chunk<<<nch, 256, 0, stream>>>(cursor, chunk, row_off, cursor, N);
      bucket_kernel<<<nb_E, 256, 0, stream>>>(rows, cols, vals, cursor, pairs, E);

      int sblocks = (N + 3) / 4;
      if (bf16_ok) {
        gemm_xw_bf16<<<512, 256, 0, stream>>>(x, wf, xi, N);
        spmm_csr_bf16<<<sblocks, 256, 0, stream>>>(xi, row_off, pairs, out, N, 0, N);
      } else {
        spmm_csr<<<sblocks, 256, 0, stream>>>(x, row_off, pairs, out, N);
        long long Mtotal = (long long)KCH * N;
        int mblocks = (int)((Mtotal + 31) / 32);
        gemm_relu_inplace<<<mblocks, 256, 0, stream>>>(out, W, Mtotal);
      }
    }
  } else {
    long long n4 = (long long)out_size / 4;
    int zblocks = (int)((n4 + 255) / 256);
    zero_kernel<<<zblocks, 256, 0, stream>>>((float4*)out, n4);
    long long total_threads = (long long)E * 64;
    int sblocks = (int)((total_threads + 255) / 256);
    scatter_spmm_kernel<<<sblocks, 256, 0, stream>>>(x, rows, cols, vals, out, E, N);
    long long Mtotal = (long long)KCH * N;
    int mblocks = (int)((Mtotal + 31) / 32);
    gemm_relu_inplace<<<mblocks, 256, 0, stream>>>(out, W, Mtotal);
  }
}